// Round 1
// baseline (2259.913 us; speedup 1.0000x reference)
//
#include <hip/hip_runtime.h>
#include <hip/hip_bf16.h>

typedef unsigned int u32;
typedef unsigned short u16;

// ---------------- problem constants ----------------
#define NLAB 20

#define M_1 200000
#define C_1 64
#define Z_1 16
#define Y_1 128
#define X_1 128

#define M_2 100000
#define C_2 128
#define Z_2 8
#define Y_2 64
#define X_2 64

#define M_3 50000
#define C_3 256
#define Z_3 4
#define Y_3 32
#define X_3 32

// output float offsets (concatenated in reference return order)
#define O_BEV1 0
#define O_BEV2 2097152
#define O_BEV3 3145728
#define O_BEV_END 3670016   // 14336 * 256
#define O_LOG1 3670016
#define O_LOG2 7470016
#define O_LOG3 9370016
#define O_LBL1 10320016
#define O_LBL2 10520016
#define O_LBL3 10620016

// ws layout.  Phase 1: int counts [0 .. 47.8MB).  Phase 2 (after k_lbl
// consumed the counts): bf16 h matrices reuse the same bytes [0 .. 44.8MB).
// Partials + stats live above at float offset 12,000,000 (byte 48MB).
// Peak ws requirement: ~49.5 MB.
#define WC1 0
#define WC2 10485760
#define WC3 11796480
#define W_COUNT_BYTES 47841280ull
// bf16 (u16) element offsets for h
#define WH1 0
#define WH2 12800000
#define WH3 19200000
// float element offsets
#define WPART 12000000
#define WP1 0
#define WP2 200064
#define WP3 300160
#define WSTATS 12350208

// gemm: 128 rows per block (4 waves x 32 rows)
#define GB1 1563
#define GB2 782
#define GB3 391
// head/lbl: 256 rows per block
#define HB1 782
#define HB2 391
#define HB3 196

// ---------------- bev ----------------
__global__ __launch_bounds__(256) void k_init_bev(float* __restrict__ out) {
  int i = blockIdx.x * 256 + threadIdx.x;
  out[i] = __uint_as_float(0xff800000u);  // -inf
}

__global__ __launch_bounds__(256) void k_bev(
    const float* __restrict__ f1, const float* __restrict__ f2, const float* __restrict__ f3,
    const int* __restrict__ co1, const int* __restrict__ co2, const int* __restrict__ co3,
    float* __restrict__ out)
{
  int blk = blockIdx.x;
  const float* f; const int* co; int logC, Y, X; long obase; int local;
  if (blk < 50000)       { f = f1; co = co1; logC = 6; Y = Y_1; X = X_1; obase = O_BEV1; local = blk * 256 + threadIdx.x; }
  else if (blk < 100000) { f = f2; co = co2; logC = 7; Y = Y_2; X = X_2; obase = O_BEV2; local = (blk - 50000) * 256 + threadIdx.x; }
  else                   { f = f3; co = co3; logC = 8; Y = Y_3; X = X_3; obase = O_BEV3; local = (blk - 100000) * 256 + threadIdx.x; }
  int p = local >> logC;
  int c = local & ((1 << logC) - 1);
  int b = co[p * 4 + 0], y = co[p * 4 + 2], x = co[p * 4 + 3];
  int C = 1 << logC;
  long oi = obase + (long)(((b * C + c) * Y + y) * X + x);
  float v = f[local];
  float* addr = out + oi;
  // float atomic max: signed-int max for v>=0, unsigned-int min for v<0.
  // Both are monotone toward larger float given -inf init; mixed interleave safe.
  if (v >= 0.f) atomicMax((int*)addr, __float_as_int(v));
  else          atomicMin((u32*)addr, __float_as_uint(v));
}

__global__ __launch_bounds__(256) void k_fix(float* __restrict__ out) {
  int i = blockIdx.x * 256 + threadIdx.x;
  u32 u = __float_as_uint(out[i]);
  if ((u & 0x7f800000u) == 0x7f800000u) out[i] = 0.f;  // inf/nan -> 0 (empty cells)
}

// ---------------- semantic target ----------------
__global__ __launch_bounds__(256) void k_count(
    const int* __restrict__ i2, const int* __restrict__ i4, const int* __restrict__ i8,
    const int* __restrict__ lab, int* __restrict__ cnt)
{
  int blk = blockIdx.x;
  const int* pc; int Z, Y, X; int* base; int i;
  if (blk < 1954)      { pc = i2; Z = Z_1; Y = Y_1; X = X_1; base = cnt + WC1; i = blk * 256 + threadIdx.x; }
  else if (blk < 3908) { pc = i4; Z = Z_2; Y = Y_2; X = X_2; base = cnt + WC2; i = (blk - 1954) * 256 + threadIdx.x; }
  else                 { pc = i8; Z = Z_3; Y = Y_3; X = X_3; base = cnt + WC3; i = (blk - 3908) * 256 + threadIdx.x; }
  if (i >= 500000) return;
  int b = pc[i * 4], z = pc[i * 4 + 1], y = pc[i * 4 + 2], x = pc[i * 4 + 3];
  int lin = ((b * Z + z) * Y + y) * X + x;
  atomicAdd(base + lin * NLAB + lab[i], 1);
}

__global__ __launch_bounds__(256) void k_lbl(
    const int* __restrict__ fc1, const int* __restrict__ fc2, const int* __restrict__ fc3,
    const int* __restrict__ cnt, float* __restrict__ out)
{
  int blk = blockIdx.x;
  const int* fc; int Z, Y, X, M; const int* base; long lbase; int m;
  if (blk < HB1)            { fc = fc1; Z = Z_1; Y = Y_1; X = X_1; M = M_1; base = cnt + WC1; lbase = O_LBL1; m = blk * 256 + threadIdx.x; }
  else if (blk < HB1 + HB2) { fc = fc2; Z = Z_2; Y = Y_2; X = X_2; M = M_2; base = cnt + WC2; lbase = O_LBL2; m = (blk - HB1) * 256 + threadIdx.x; }
  else                      { fc = fc3; Z = Z_3; Y = Y_3; X = X_3; M = M_3; base = cnt + WC3; lbase = O_LBL3; m = (blk - HB1 - HB2) * 256 + threadIdx.x; }
  if (m >= M) return;
  int b = fc[m * 4], z = fc[m * 4 + 1], y = fc[m * 4 + 2], x = fc[m * 4 + 3];
  int lin = ((b * Z + z) * Y + y) * X + x;
  const int* cp = base + lin * NLAB;
  int best = cp[0]; int bi = 0;
#pragma unroll
  for (int n = 1; n < NLAB; n++) { int cc = cp[n]; if (cc > best) { best = cc; bi = n; } }
  // argmax of all-zero row is 0, matching where(occ, maj, 0)
  out[lbase + m] = (float)bi;
}

// ---------------- head GEMM (h = x @ w1), col-stat partials, bf16 h ----------------
// lane = output column n (N=64 == wavefront). w1 tile in VGPRs (per-lane column),
// x row elements are wave-uniform -> scalar loads, FMA with SGPR operand.
__global__ __launch_bounds__(256) void k_gemm(
    const float* __restrict__ x1, const float* __restrict__ x2, const float* __restrict__ x3,
    const float* __restrict__ w1a, const float* __restrict__ w1b, const float* __restrict__ w1c,
    __hip_bfloat16* __restrict__ hbuf, float* __restrict__ part)
{
  int blk = blockIdx.x;
  const float* x; const float* w1; __hip_bfloat16* h; float* pp; int Cin, M, bl;
  if (blk < GB1)            { x = x1; w1 = w1a; h = hbuf + WH1; pp = part + WP1; Cin = C_1; M = M_1; bl = blk; }
  else if (blk < GB1 + GB2) { x = x2; w1 = w1b; h = hbuf + WH2; pp = part + WP2; Cin = C_2; M = M_2; bl = blk - GB1; }
  else                      { x = x3; w1 = w1c; h = hbuf + WH3; pp = part + WP3; Cin = C_3; M = M_3; bl = blk - GB1 - GB2; }
  int tid = threadIdx.x;
  int lane = tid & 63;
  int wv = __builtin_amdgcn_readfirstlane(tid >> 6);  // force wave-uniform SGPR
  int rowbase = bl * 128 + wv * 32;

  float acc[32];
#pragma unroll
  for (int r = 0; r < 32; r++) acc[r] = 0.f;

  int ktiles = Cin >> 5;
  for (int kt = 0; kt < ktiles; kt++) {
    float w1r[32];
#pragma unroll
    for (int k = 0; k < 32; k++) w1r[k] = w1[(kt * 32 + k) * 64 + lane];
#pragma unroll
    for (int r = 0; r < 32; r++) {
      int row = rowbase + r;
      if (row < M) {
        const float* xp = x + (size_t)row * Cin + kt * 32;  // wave-uniform address
#pragma unroll
        for (int k = 0; k < 32; k++) acc[r] = fmaf(xp[k], w1r[k], acc[r]);
      }
    }
  }

  float s = 0.f, ss = 0.f;
#pragma unroll
  for (int r = 0; r < 32; r++) {
    int row = rowbase + r;
    if (row < M) {
      float v = acc[r];
      s += v; ss = fmaf(v, v, ss);
      h[(size_t)row * 64 + lane] = __float2bfloat16(v);
    }
  }
  __shared__ float red[8][64];
  red[wv][lane] = s;
  red[4 + wv][lane] = ss;
  __syncthreads();
  if (tid < 64) {
    pp[bl * 128 + tid] = red[0][tid] + red[1][tid] + red[2][tid] + red[3][tid];
  } else if (tid < 128) {
    int n = tid - 64;
    pp[bl * 128 + 64 + n] = red[4][n] + red[5][n] + red[6][n] + red[7][n];
  }
}

__global__ void k_stats(const float* __restrict__ part, float* __restrict__ stats) {
  int sc = blockIdx.x; int t = threadIdx.x;
  int nb; const float* p; float invM;
  if (sc == 0)      { nb = GB1; p = part + WP1; invM = 1.f / M_1; }
  else if (sc == 1) { nb = GB2; p = part + WP2; invM = 1.f / M_2; }
  else              { nb = GB3; p = part + WP3; invM = 1.f / M_3; }
  float acc = 0.f;
  for (int b = 0; b < nb; b++) acc += p[b * 128 + t];
  __shared__ float red[128];
  red[t] = acc;
  __syncthreads();
  if (t < 64) {
    float mu  = red[t] * invM;
    float var = red[64 + t] * invM - mu * mu;
    stats[sc * 128 + t]      = mu;
    stats[sc * 128 + 64 + t] = rsqrtf(var + 1e-5f);
  }
}

// ---------------- head epilogue: normalize -> leaky -> @ w2 + b2 ----------------
__global__ __launch_bounds__(256) void k_head(
    const u16* __restrict__ hbuf, const float* __restrict__ stats,
    const float* __restrict__ g1, const float* __restrict__ bb1, const float* __restrict__ w21, const float* __restrict__ c21,
    const float* __restrict__ g4, const float* __restrict__ bb4, const float* __restrict__ w24, const float* __restrict__ c24,
    const float* __restrict__ g8, const float* __restrict__ bb8, const float* __restrict__ w28, const float* __restrict__ c28,
    float* __restrict__ out)
{
  int blk = blockIdx.x;
  const u16* h; const float* st; const float* g; const float* bb; const float* w2; const float* b2;
  int M; long obase; int m;
  if (blk < HB1)            { h = hbuf + WH1; st = stats;       g = g1; bb = bb1; w2 = w21; b2 = c21; M = M_1; obase = O_LOG1; m = blk * 256 + threadIdx.x; }
  else if (blk < HB1 + HB2) { h = hbuf + WH2; st = stats + 128; g = g4; bb = bb4; w2 = w24; b2 = c24; M = M_2; obase = O_LOG2; m = (blk - HB1) * 256 + threadIdx.x; }
  else                      { h = hbuf + WH3; st = stats + 256; g = g8; bb = bb8; w2 = w28; b2 = c28; M = M_3; obase = O_LOG3; m = (blk - HB1 - HB2) * 256 + threadIdx.x; }
  if (m >= M) return;
  const uint4* hp = (const uint4*)(h + (size_t)m * 64);
  float acc[19];
#pragma unroll
  for (int n = 0; n < 19; n++) acc[n] = 0.f;
#pragma unroll
  for (int i = 0; i < 8; i++) {
    uint4 q = hp[i];
    u32 uu[4] = { q.x, q.y, q.z, q.w };
#pragma unroll
    for (int t = 0; t < 4; t++) {
      int j = i * 8 + t * 2;
      float f0 = __uint_as_float(uu[t] << 16);          // bf16 -> f32 exact
      float f1 = __uint_as_float(uu[t] & 0xffff0000u);
      float a0 = fmaf((f0 - st[j])     * st[64 + j],     g[j],     bb[j]);
      a0 = a0 >= 0.f ? a0 : 0.1f * a0;
      float a1 = fmaf((f1 - st[j + 1]) * st[64 + j + 1], g[j + 1], bb[j + 1]);
      a1 = a1 >= 0.f ? a1 : 0.1f * a1;
#pragma unroll
      for (int n = 0; n < 19; n++) acc[n] = fmaf(a0, w2[j * 19 + n], acc[n]);
#pragma unroll
      for (int n = 0; n < 19; n++) acc[n] = fmaf(a1, w2[(j + 1) * 19 + n], acc[n]);
    }
  }
  float* op = out + obase + (size_t)m * 19;
#pragma unroll
  for (int n = 0; n < 19; n++) op[n] = acc[n] + b2[n];
}

// ---------------- launch ----------------
extern "C" void kernel_launch(void* const* d_in, const int* in_sizes, int n_in,
                              void* d_out, int out_size, void* d_ws, size_t ws_size,
                              hipStream_t stream) {
  (void)in_sizes; (void)n_in; (void)out_size; (void)ws_size;
  const float* p1 = (const float*)d_in[0];
  const float* p2 = (const float*)d_in[1];
  const float* p3 = (const float*)d_in[2];
  const int* vc1  = (const int*)d_in[3];
  const int* vc2  = (const int*)d_in[4];
  const int* vc3  = (const int*)d_in[5];
  const int* i2   = (const int*)d_in[6];
  const int* i4   = (const int*)d_in[7];
  const int* i8   = (const int*)d_in[8];
  const int* lab  = (const int*)d_in[9];
  const float* h2w1 = (const float*)d_in[10]; const float* h2g = (const float*)d_in[11];
  const float* h2b  = (const float*)d_in[12]; const float* h2w2 = (const float*)d_in[13];
  const float* h2b2 = (const float*)d_in[14];
  const float* h4w1 = (const float*)d_in[15]; const float* h4g = (const float*)d_in[16];
  const float* h4b  = (const float*)d_in[17]; const float* h4w2 = (const float*)d_in[18];
  const float* h4b2 = (const float*)d_in[19];
  const float* h8w1 = (const float*)d_in[20]; const float* h8g = (const float*)d_in[21];
  const float* h8b  = (const float*)d_in[22]; const float* h8w2 = (const float*)d_in[23];
  const float* h8b2 = (const float*)d_in[24];

  float* out = (float*)d_out;
  int* wsi = (int*)d_ws;
  float* wsf = (float*)d_ws;
  __hip_bfloat16* wsh = (__hip_bfloat16*)d_ws;

  // 1) zero the label histograms
  hipMemsetAsync(d_ws, 0, W_COUNT_BYTES, stream);
  // 2) bev: init to -inf, scatter atomic-max, fix empties to 0
  k_init_bev<<<14336, 256, 0, stream>>>(out);
  k_bev<<<150000, 256, 0, stream>>>(p1, p2, p3, vc1, vc2, vc3, out);
  k_fix<<<14336, 256, 0, stream>>>(out);
  // 3) semantic targets
  k_count<<<5862, 256, 0, stream>>>(i2, i4, i8, lab, wsi);
  k_lbl<<<HB1 + HB2 + HB3, 256, 0, stream>>>(vc1, vc2, vc3, wsi, out);
  // 4) heads (h reuses the counts bytes; counts fully consumed by k_lbl above)
  k_gemm<<<GB1 + GB2 + GB3, 256, 0, stream>>>(p1, p2, p3, h2w1, h4w1, h8w1, wsh, wsf + WPART);
  k_stats<<<3, 128, 0, stream>>>(wsf + WPART, wsf + WSTATS);
  k_head<<<HB1 + HB2 + HB3, 256, 0, stream>>>((const u16*)d_ws, wsf + WSTATS,
      h2g, h2b, h2w2, h2b2, h4g, h4b, h4w2, h4b2, h8g, h8b, h8w2, h8b2, out);
}

// Round 2
// 1076.191 us; speedup vs baseline: 2.0999x; 2.0999x over previous
//
#include <hip/hip_runtime.h>
#include <hip/hip_bf16.h>

typedef unsigned int u32;
typedef unsigned short u16;

// ---------------- problem constants ----------------
#define NLAB 20

#define M_1 200000
#define C_1 64
#define Z_1 16
#define Y_1 128
#define X_1 128

#define M_2 100000
#define C_2 128
#define Z_2 8
#define Y_2 64
#define X_2 64

#define M_3 50000
#define C_3 256
#define Z_3 4
#define Y_3 32
#define X_3 32

// output float offsets (concatenated in reference return order)
#define O_BEV1 0
#define O_BEV2 2097152
#define O_BEV3 3145728
#define O_LOG1 3670016
#define O_LOG2 7470016
#define O_LOG3 9370016
#define O_LBL1 10320016
#define O_LBL2 10520016
#define O_LBL3 10620016

// ---------------- ws layout (phase-reused, stream-ordered) ----------------
// Phase A (BEV sort+gather): int offsets
//   WB_CNT  [0 .. 43008)        per-cell point counts (zeroed via memset)
//   WB_CUR  [43008 .. 86016)    exclusive-prefix cursors (written by scan)
//   WB_PIDX [86016 .. 436016)   sorted point indices
// Phase B (labels): int counts [0 .. 11,960,320) ints (47.8MB)
// Phase C (heads): bf16 h reuses [0 .. 44.8MB); partials/stats above 48MB.
#define WB_CNT 0
#define WB_CUR 43008
#define WB_PIDX 86016
#define NCELLS 43008
#define SB1 0
#define SB2 32768
#define SB3 40960

#define WC1 0
#define WC2 10485760
#define WC3 11796480
#define W_COUNT_BYTES 47841280ull
// bf16 (u16) element offsets for h
#define WH1 0
#define WH2 12800000
#define WH3 19200000
// float element offsets
#define WPART 12000000
#define WP1 0
#define WP2 200064
#define WP3 300160
#define WSTATS 12350208

// gemm: 128 rows per block (4 waves x 32 rows)
#define GB1 1563
#define GB2 782
#define GB3 391
// head/lbl/point-loop: 256 rows per block
#define HB1 782
#define HB2 391
#define HB3 196

// ---------------- BEV phase A: count points per cell ----------------
__global__ __launch_bounds__(256) void k_cellcount(
    const int* __restrict__ co1, const int* __restrict__ co2, const int* __restrict__ co3,
    int* __restrict__ cnt)
{
  int blk = blockIdx.x;
  const int* co; int Y, X, M, base, m;
  if (blk < HB1)            { co = co1; Y = Y_1; X = X_1; M = M_1; base = SB1; m = blk * 256 + threadIdx.x; }
  else if (blk < HB1 + HB2) { co = co2; Y = Y_2; X = X_2; M = M_2; base = SB2; m = (blk - HB1) * 256 + threadIdx.x; }
  else                      { co = co3; Y = Y_3; X = X_3; M = M_3; base = SB3; m = (blk - HB1 - HB2) * 256 + threadIdx.x; }
  if (m >= M) return;
  int b = co[m * 4], y = co[m * 4 + 2], x = co[m * 4 + 3];
  atomicAdd(cnt + base + (b * Y + y) * X + x, 1);
}

// ---------------- BEV phase B: exclusive prefix scan over all cells ----------------
__global__ __launch_bounds__(1024) void k_scan(const int* __restrict__ cnt, int* __restrict__ cur) {
  int t = threadIdx.x;            // 1024 threads, 42 cells each = 43008
  int local[42];
  int s = 0;
#pragma unroll
  for (int j = 0; j < 42; j++) { local[j] = cnt[t * 42 + j]; s += local[j]; }
  __shared__ int red[1024];
  red[t] = s;
  __syncthreads();
  for (int off = 1; off < 1024; off <<= 1) {
    int v = (t >= off) ? red[t - off] : 0;
    __syncthreads();
    red[t] += v;
    __syncthreads();
  }
  int base = red[t] - s;          // exclusive prefix of this thread's chunk
#pragma unroll
  for (int j = 0; j < 42; j++) { cur[t * 42 + j] = base; base += local[j]; }
}

// ---------------- BEV phase C: scatter point indices into sorted order ----------------
__global__ __launch_bounds__(256) void k_scatter(
    const int* __restrict__ co1, const int* __restrict__ co2, const int* __restrict__ co3,
    int* __restrict__ cur, int* __restrict__ pidx)
{
  int blk = blockIdx.x;
  const int* co; int Y, X, M, base, m;
  if (blk < HB1)            { co = co1; Y = Y_1; X = X_1; M = M_1; base = SB1; m = blk * 256 + threadIdx.x; }
  else if (blk < HB1 + HB2) { co = co2; Y = Y_2; X = X_2; M = M_2; base = SB2; m = (blk - HB1) * 256 + threadIdx.x; }
  else                      { co = co3; Y = Y_3; X = X_3; M = M_3; base = SB3; m = (blk - HB1 - HB2) * 256 + threadIdx.x; }
  if (m >= M) return;
  int b = co[m * 4], y = co[m * 4 + 2], x = co[m * 4 + 3];
  int slot = atomicAdd(cur + base + (b * Y + y) * X + x, 1);
  pidx[slot] = m;
}

// ---------------- BEV phase D: gather-max per cell ----------------
// scale 1: C=64, wave per cell, 4 cells (consecutive x) per block
__global__ __launch_bounds__(256) void k_bevg1(
    const float* __restrict__ f, const int* __restrict__ cnt, const int* __restrict__ cur,
    const int* __restrict__ pidx, float* __restrict__ out)
{
  int tid = threadIdx.x, lane = tid & 63, wv = tid >> 6;
  int cellbase = blockIdx.x * 4;
  int cell = cellbase + wv;
  int n = cnt[SB1 + cell], end = cur[SB1 + cell], start = end - n;
  float acc = __uint_as_float(0xff800000u);
  for (int i = start; i < end; i++) {
    int p = pidx[i];
    acc = fmaxf(acc, f[(size_t)p * 64 + lane]);
  }
  float val = (n > 0) ? acc : 0.f;
  __shared__ float tile[4][72];          // stride 72 -> 2-way max on read side (free)
  tile[wv][lane] = val;
  __syncthreads();
  int c = tid >> 2, xi = tid & 3;
  int x0 = cellbase & 127, y = (cellbase >> 7) & 127, b = cellbase >> 14;
  out[O_BEV1 + ((((b * 64 + c) * 128 + y) * 128) + x0 + xi)] = tile[xi][c];
}

// scale 2: C=128, half-block (2 waves) per cell, 2 cells per block
__global__ __launch_bounds__(256) void k_bevg2(
    const float* __restrict__ f, const int* __restrict__ cnt, const int* __restrict__ cur,
    const int* __restrict__ pidx, float* __restrict__ out)
{
  int tid = threadIdx.x, ch = tid & 127, sub = tid >> 7;
  int cellbase = blockIdx.x * 2;
  int cell = cellbase + sub;
  int n = cnt[SB2 + cell], end = cur[SB2 + cell], start = end - n;
  float acc = __uint_as_float(0xff800000u);
  for (int i = start; i < end; i++) {
    int p = pidx[i];
    acc = fmaxf(acc, f[(size_t)p * 128 + ch]);
  }
  float val = (n > 0) ? acc : 0.f;
  __shared__ float tile[2][128];
  tile[sub][ch] = val;
  __syncthreads();
  int c = tid >> 1, xi = tid & 1;
  int x0 = cellbase & 63, y = (cellbase >> 6) & 63, b = cellbase >> 12;
  out[O_BEV2 + ((((b * 128 + c) * 64 + y) * 64) + x0 + xi)] = tile[xi][c];
}

// scale 3: C=256, whole block per cell, 2 cells sequentially per block
__global__ __launch_bounds__(256) void k_bevg3(
    const float* __restrict__ f, const int* __restrict__ cnt, const int* __restrict__ cur,
    const int* __restrict__ pidx, float* __restrict__ out)
{
  int tid = threadIdx.x;
  int cellbase = blockIdx.x * 2;
  __shared__ float tile[2][256];
#pragma unroll
  for (int s = 0; s < 2; s++) {
    int cell = cellbase + s;
    int n = cnt[SB3 + cell], end = cur[SB3 + cell], start = end - n;
    float acc = __uint_as_float(0xff800000u);
    for (int i = start; i < end; i++) {
      int p = pidx[i];
      acc = fmaxf(acc, f[(size_t)p * 256 + tid]);
    }
    tile[s][tid] = (n > 0) ? acc : 0.f;
  }
  __syncthreads();
  int x0 = cellbase & 31, y = (cellbase >> 5) & 31, b = cellbase >> 10;
#pragma unroll
  for (int r = 0; r < 2; r++) {
    int c = (tid >> 1) + r * 128, xi = tid & 1;
    out[O_BEV3 + ((((b * 256 + c) * 32 + y) * 32) + x0 + xi)] = tile[xi][c];
  }
}

// ---------------- semantic target ----------------
__global__ __launch_bounds__(256) void k_count(
    const int* __restrict__ i2, const int* __restrict__ i4, const int* __restrict__ i8,
    const int* __restrict__ lab, int* __restrict__ cnt)
{
  int blk = blockIdx.x;
  const int* pc; int Z, Y, X; int* base; int i;
  if (blk < 1954)      { pc = i2; Z = Z_1; Y = Y_1; X = X_1; base = cnt + WC1; i = blk * 256 + threadIdx.x; }
  else if (blk < 3908) { pc = i4; Z = Z_2; Y = Y_2; X = X_2; base = cnt + WC2; i = (blk - 1954) * 256 + threadIdx.x; }
  else                 { pc = i8; Z = Z_3; Y = Y_3; X = X_3; base = cnt + WC3; i = (blk - 3908) * 256 + threadIdx.x; }
  if (i >= 500000) return;
  int b = pc[i * 4], z = pc[i * 4 + 1], y = pc[i * 4 + 2], x = pc[i * 4 + 3];
  int lin = ((b * Z + z) * Y + y) * X + x;
  atomicAdd(base + lin * NLAB + lab[i], 1);
}

__global__ __launch_bounds__(256) void k_lbl(
    const int* __restrict__ fc1, const int* __restrict__ fc2, const int* __restrict__ fc3,
    const int* __restrict__ cnt, float* __restrict__ out)
{
  int blk = blockIdx.x;
  const int* fc; int Z, Y, X, M; const int* base; long lbase; int m;
  if (blk < HB1)            { fc = fc1; Z = Z_1; Y = Y_1; X = X_1; M = M_1; base = cnt + WC1; lbase = O_LBL1; m = blk * 256 + threadIdx.x; }
  else if (blk < HB1 + HB2) { fc = fc2; Z = Z_2; Y = Y_2; X = X_2; M = M_2; base = cnt + WC2; lbase = O_LBL2; m = (blk - HB1) * 256 + threadIdx.x; }
  else                      { fc = fc3; Z = Z_3; Y = Y_3; X = X_3; M = M_3; base = cnt + WC3; lbase = O_LBL3; m = (blk - HB1 - HB2) * 256 + threadIdx.x; }
  if (m >= M) return;
  int b = fc[m * 4], z = fc[m * 4 + 1], y = fc[m * 4 + 2], x = fc[m * 4 + 3];
  int lin = ((b * Z + z) * Y + y) * X + x;
  const int* cp = base + lin * NLAB;
  int best = cp[0]; int bi = 0;
#pragma unroll
  for (int n = 1; n < NLAB; n++) { int cc = cp[n]; if (cc > best) { best = cc; bi = n; } }
  out[lbase + m] = (float)bi;
}

// ---------------- head GEMM (h = x @ w1), col-stat partials, bf16 h ----------------
__global__ __launch_bounds__(256) void k_gemm(
    const float* __restrict__ x1, const float* __restrict__ x2, const float* __restrict__ x3,
    const float* __restrict__ w1a, const float* __restrict__ w1b, const float* __restrict__ w1c,
    __hip_bfloat16* __restrict__ hbuf, float* __restrict__ part)
{
  int blk = blockIdx.x;
  const float* x; const float* w1; __hip_bfloat16* h; float* pp; int Cin, M, bl;
  if (blk < GB1)            { x = x1; w1 = w1a; h = hbuf + WH1; pp = part + WP1; Cin = C_1; M = M_1; bl = blk; }
  else if (blk < GB1 + GB2) { x = x2; w1 = w1b; h = hbuf + WH2; pp = part + WP2; Cin = C_2; M = M_2; bl = blk - GB1; }
  else                      { x = x3; w1 = w1c; h = hbuf + WH3; pp = part + WP3; Cin = C_3; M = M_3; bl = blk - GB1 - GB2; }
  int tid = threadIdx.x;
  int lane = tid & 63;
  int wv = __builtin_amdgcn_readfirstlane(tid >> 6);
  int rowbase = bl * 128 + wv * 32;

  float acc[32];
#pragma unroll
  for (int r = 0; r < 32; r++) acc[r] = 0.f;

  int ktiles = Cin >> 5;
  for (int kt = 0; kt < ktiles; kt++) {
    float w1r[32];
#pragma unroll
    for (int k = 0; k < 32; k++) w1r[k] = w1[(kt * 32 + k) * 64 + lane];
#pragma unroll
    for (int r = 0; r < 32; r++) {
      int row = rowbase + r;
      if (row < M) {
        const float* xp = x + (size_t)row * Cin + kt * 32;  // wave-uniform address
#pragma unroll
        for (int k = 0; k < 32; k++) acc[r] = fmaf(xp[k], w1r[k], acc[r]);
      }
    }
  }

  float s = 0.f, ss = 0.f;
#pragma unroll
  for (int r = 0; r < 32; r++) {
    int row = rowbase + r;
    if (row < M) {
      float v = acc[r];
      s += v; ss = fmaf(v, v, ss);
      h[(size_t)row * 64 + lane] = __float2bfloat16(v);
    }
  }
  __shared__ float red[8][64];
  red[wv][lane] = s;
  red[4 + wv][lane] = ss;
  __syncthreads();
  if (tid < 64) {
    pp[bl * 128 + tid] = red[0][tid] + red[1][tid] + red[2][tid] + red[3][tid];
  } else if (tid < 128) {
    int n = tid - 64;
    pp[bl * 128 + 64 + n] = red[4][n] + red[5][n] + red[6][n] + red[7][n];
  }
}

__global__ void k_stats(const float* __restrict__ part, float* __restrict__ stats) {
  int sc = blockIdx.x; int t = threadIdx.x;
  int nb; const float* p; float invM;
  if (sc == 0)      { nb = GB1; p = part + WP1; invM = 1.f / M_1; }
  else if (sc == 1) { nb = GB2; p = part + WP2; invM = 1.f / M_2; }
  else              { nb = GB3; p = part + WP3; invM = 1.f / M_3; }
  float acc = 0.f;
  for (int b = 0; b < nb; b++) acc += p[b * 128 + t];
  __shared__ float red[128];
  red[t] = acc;
  __syncthreads();
  if (t < 64) {
    float mu  = red[t] * invM;
    float var = red[64 + t] * invM - mu * mu;
    stats[sc * 128 + t]      = mu;
    stats[sc * 128 + 64 + t] = rsqrtf(var + 1e-5f);
  }
}

// ---------------- head epilogue: normalize -> leaky -> @ w2 + b2 ----------------
__global__ __launch_bounds__(256) void k_head(
    const u16* __restrict__ hbuf, const float* __restrict__ stats,
    const float* __restrict__ g1, const float* __restrict__ bb1, const float* __restrict__ w21, const float* __restrict__ c21,
    const float* __restrict__ g4, const float* __restrict__ bb4, const float* __restrict__ w24, const float* __restrict__ c24,
    const float* __restrict__ g8, const float* __restrict__ bb8, const float* __restrict__ w28, const float* __restrict__ c28,
    float* __restrict__ out)
{
  int blk = blockIdx.x;
  const u16* h; const float* st; const float* g; const float* bb; const float* w2; const float* b2;
  int M; long obase; int m;
  if (blk < HB1)            { h = hbuf + WH1; st = stats;       g = g1; bb = bb1; w2 = w21; b2 = c21; M = M_1; obase = O_LOG1; m = blk * 256 + threadIdx.x; }
  else if (blk < HB1 + HB2) { h = hbuf + WH2; st = stats + 128; g = g4; bb = bb4; w2 = w24; b2 = c24; M = M_2; obase = O_LOG2; m = (blk - HB1) * 256 + threadIdx.x; }
  else                      { h = hbuf + WH3; st = stats + 256; g = g8; bb = bb8; w2 = w28; b2 = c28; M = M_3; obase = O_LOG3; m = (blk - HB1 - HB2) * 256 + threadIdx.x; }
  if (m >= M) return;
  const uint4* hp = (const uint4*)(h + (size_t)m * 64);
  float acc[19];
#pragma unroll
  for (int n = 0; n < 19; n++) acc[n] = 0.f;
#pragma unroll
  for (int i = 0; i < 8; i++) {
    uint4 q = hp[i];
    u32 uu[4] = { q.x, q.y, q.z, q.w };
#pragma unroll
    for (int t = 0; t < 4; t++) {
      int j = i * 8 + t * 2;
      float f0 = __uint_as_float(uu[t] << 16);
      float f1 = __uint_as_float(uu[t] & 0xffff0000u);
      float a0 = fmaf((f0 - st[j])     * st[64 + j],     g[j],     bb[j]);
      a0 = a0 >= 0.f ? a0 : 0.1f * a0;
      float a1 = fmaf((f1 - st[j + 1]) * st[64 + j + 1], g[j + 1], bb[j + 1]);
      a1 = a1 >= 0.f ? a1 : 0.1f * a1;
#pragma unroll
      for (int n = 0; n < 19; n++) acc[n] = fmaf(a0, w2[j * 19 + n], acc[n]);
#pragma unroll
      for (int n = 0; n < 19; n++) acc[n] = fmaf(a1, w2[(j + 1) * 19 + n], acc[n]);
    }
  }
  float* op = out + obase + (size_t)m * 19;
#pragma unroll
  for (int n = 0; n < 19; n++) op[n] = acc[n] + b2[n];
}

// ---------------- launch ----------------
extern "C" void kernel_launch(void* const* d_in, const int* in_sizes, int n_in,
                              void* d_out, int out_size, void* d_ws, size_t ws_size,
                              hipStream_t stream) {
  (void)in_sizes; (void)n_in; (void)out_size; (void)ws_size;
  const float* p1 = (const float*)d_in[0];
  const float* p2 = (const float*)d_in[1];
  const float* p3 = (const float*)d_in[2];
  const int* vc1  = (const int*)d_in[3];
  const int* vc2  = (const int*)d_in[4];
  const int* vc3  = (const int*)d_in[5];
  const int* i2   = (const int*)d_in[6];
  const int* i4   = (const int*)d_in[7];
  const int* i8   = (const int*)d_in[8];
  const int* lab  = (const int*)d_in[9];
  const float* h2w1 = (const float*)d_in[10]; const float* h2g = (const float*)d_in[11];
  const float* h2b  = (const float*)d_in[12]; const float* h2w2 = (const float*)d_in[13];
  const float* h2b2 = (const float*)d_in[14];
  const float* h4w1 = (const float*)d_in[15]; const float* h4g = (const float*)d_in[16];
  const float* h4b  = (const float*)d_in[17]; const float* h4w2 = (const float*)d_in[18];
  const float* h4b2 = (const float*)d_in[19];
  const float* h8w1 = (const float*)d_in[20]; const float* h8g = (const float*)d_in[21];
  const float* h8b  = (const float*)d_in[22]; const float* h8w2 = (const float*)d_in[23];
  const float* h8b2 = (const float*)d_in[24];

  float* out = (float*)d_out;
  int* wsi = (int*)d_ws;
  float* wsf = (float*)d_ws;
  __hip_bfloat16* wsh = (__hip_bfloat16*)d_ws;

  // ---- BEV: counting-sort + gather (no global atomic-max) ----
  hipMemsetAsync(wsi + WB_CNT, 0, NCELLS * sizeof(int), stream);
  k_cellcount<<<HB1 + HB2 + HB3, 256, 0, stream>>>(vc1, vc2, vc3, wsi + WB_CNT);
  k_scan<<<1, 1024, 0, stream>>>(wsi + WB_CNT, wsi + WB_CUR);
  k_scatter<<<HB1 + HB2 + HB3, 256, 0, stream>>>(vc1, vc2, vc3, wsi + WB_CUR, wsi + WB_PIDX);
  k_bevg1<<<8192, 256, 0, stream>>>(p1, wsi + WB_CNT, wsi + WB_CUR, wsi + WB_PIDX, out);
  k_bevg2<<<4096, 256, 0, stream>>>(p2, wsi + WB_CNT, wsi + WB_CUR, wsi + WB_PIDX, out);
  k_bevg3<<<1024, 256, 0, stream>>>(p3, wsi + WB_CNT, wsi + WB_CUR, wsi + WB_PIDX, out);

  // ---- semantic targets (reuses ws bytes; stream-ordered after BEV) ----
  hipMemsetAsync(d_ws, 0, W_COUNT_BYTES, stream);
  k_count<<<5862, 256, 0, stream>>>(i2, i4, i8, lab, wsi);
  k_lbl<<<HB1 + HB2 + HB3, 256, 0, stream>>>(vc1, vc2, vc3, wsi, out);

  // ---- heads (h reuses the counts bytes; counts fully consumed by k_lbl) ----
  k_gemm<<<GB1 + GB2 + GB3, 256, 0, stream>>>(p1, p2, p3, h2w1, h4w1, h8w1, wsh, wsf + WPART);
  k_stats<<<3, 128, 0, stream>>>(wsf + WPART, wsf + WSTATS);
  k_head<<<HB1 + HB2 + HB3, 256, 0, stream>>>((const u16*)d_ws, wsf + WSTATS,
      h2g, h2b, h2w2, h2b2, h4g, h4b, h4w2, h4b2, h8g, h8b, h8w2, h8b2, out);
}

// Round 3
// 698.868 us; speedup vs baseline: 3.2337x; 1.5399x over previous
//
#include <hip/hip_runtime.h>
#include <hip/hip_bf16.h>

typedef unsigned int u32;
typedef unsigned short u16;

// ---------------- problem constants ----------------
#define NLAB 20

#define M_1 200000
#define C_1 64
#define Z_1 16
#define Y_1 128
#define X_1 128

#define M_2 100000
#define C_2 128
#define Z_2 8
#define Y_2 64
#define X_2 64

#define M_3 50000
#define C_3 256
#define Z_3 4
#define Y_3 32
#define X_3 32

// output float offsets (concatenated in reference return order)
#define O_BEV1 0
#define O_BEV2 2097152
#define O_BEV3 3145728
#define O_LOG1 3670016
#define O_LOG2 7470016
#define O_LOG3 9370016
#define O_LBL1 10320016
#define O_LBL2 10520016
#define O_LBL3 10620016

// ---------------- ws layout (phase-reused, stream-ordered) ----------------
#define WB_CNT 0
#define WB_CUR 43008
#define WB_PIDX 86016
#define NCELLS 43008
#define SB1 0
#define SB2 32768
#define SB3 40960

#define WC1 0
#define WC2 10485760
#define WC3 11796480
#define W_COUNT_BYTES 47841280ull
// bf16 (u16) element offsets for h
#define WH1 0
#define WH2 12800000
#define WH3 19200000
// float element offsets (partials transposed: sum[col*NB+bl], ss at +64*NB)
#define WPART 12000000
#define WP1 0
#define WP2 200064
#define WP3 300160
#define WSTATS 12350208

// gemm: 128 rows per block (4 waves x 32 rows)
#define GB1 1563
#define GB2 782
#define GB3 391
// head/lbl/point-loop: 256 rows per block
#define HB1 782
#define HB2 391
#define HB3 196

// ---------------- BEV phase A: count points per cell ----------------
__global__ __launch_bounds__(256) void k_cellcount(
    const int* __restrict__ co1, const int* __restrict__ co2, const int* __restrict__ co3,
    int* __restrict__ cnt)
{
  int blk = blockIdx.x;
  const int* co; int Y, X, M, base, m;
  if (blk < HB1)            { co = co1; Y = Y_1; X = X_1; M = M_1; base = SB1; m = blk * 256 + threadIdx.x; }
  else if (blk < HB1 + HB2) { co = co2; Y = Y_2; X = X_2; M = M_2; base = SB2; m = (blk - HB1) * 256 + threadIdx.x; }
  else                      { co = co3; Y = Y_3; X = X_3; M = M_3; base = SB3; m = (blk - HB1 - HB2) * 256 + threadIdx.x; }
  if (m >= M) return;
  int b = co[m * 4], y = co[m * 4 + 2], x = co[m * 4 + 3];
  atomicAdd(cnt + base + (b * Y + y) * X + x, 1);
}

// ---------------- BEV phase B: exclusive prefix scan over all cells ----------------
__global__ __launch_bounds__(1024) void k_scan(const int* __restrict__ cnt, int* __restrict__ cur) {
  int t = threadIdx.x;            // 1024 threads, 42 cells each = 43008
  int local[42];
  int s = 0;
#pragma unroll
  for (int j = 0; j < 42; j++) { local[j] = cnt[t * 42 + j]; s += local[j]; }
  __shared__ int red[1024];
  red[t] = s;
  __syncthreads();
  for (int off = 1; off < 1024; off <<= 1) {
    int v = (t >= off) ? red[t - off] : 0;
    __syncthreads();
    red[t] += v;
    __syncthreads();
  }
  int base = red[t] - s;          // exclusive prefix of this thread's chunk
#pragma unroll
  for (int j = 0; j < 42; j++) { cur[t * 42 + j] = base; base += local[j]; }
}

// ---------------- BEV phase C: scatter point indices into sorted order ----------------
__global__ __launch_bounds__(256) void k_scatter(
    const int* __restrict__ co1, const int* __restrict__ co2, const int* __restrict__ co3,
    int* __restrict__ cur, int* __restrict__ pidx)
{
  int blk = blockIdx.x;
  const int* co; int Y, X, M, base, m;
  if (blk < HB1)            { co = co1; Y = Y_1; X = X_1; M = M_1; base = SB1; m = blk * 256 + threadIdx.x; }
  else if (blk < HB1 + HB2) { co = co2; Y = Y_2; X = X_2; M = M_2; base = SB2; m = (blk - HB1) * 256 + threadIdx.x; }
  else                      { co = co3; Y = Y_3; X = X_3; M = M_3; base = SB3; m = (blk - HB1 - HB2) * 256 + threadIdx.x; }
  if (m >= M) return;
  int b = co[m * 4], y = co[m * 4 + 2], x = co[m * 4 + 3];
  int slot = atomicAdd(cur + base + (b * Y + y) * X + x, 1);
  pidx[slot] = m;
}

// ---------------- BEV phase D: gather-max per cell ----------------
__global__ __launch_bounds__(256) void k_bevg1(
    const float* __restrict__ f, const int* __restrict__ cnt, const int* __restrict__ cur,
    const int* __restrict__ pidx, float* __restrict__ out)
{
  int tid = threadIdx.x, lane = tid & 63, wv = tid >> 6;
  int cellbase = blockIdx.x * 4;
  int cell = cellbase + wv;
  int n = cnt[SB1 + cell], end = cur[SB1 + cell], start = end - n;
  float acc = __uint_as_float(0xff800000u);
  for (int i = start; i < end; i++) {
    int p = pidx[i];
    acc = fmaxf(acc, f[(size_t)p * 64 + lane]);
  }
  float val = (n > 0) ? acc : 0.f;
  __shared__ float tile[4][72];
  tile[wv][lane] = val;
  __syncthreads();
  int c = tid >> 2, xi = tid & 3;
  int x0 = cellbase & 127, y = (cellbase >> 7) & 127, b = cellbase >> 14;
  out[O_BEV1 + ((((b * 64 + c) * 128 + y) * 128) + x0 + xi)] = tile[xi][c];
}

__global__ __launch_bounds__(256) void k_bevg2(
    const float* __restrict__ f, const int* __restrict__ cnt, const int* __restrict__ cur,
    const int* __restrict__ pidx, float* __restrict__ out)
{
  int tid = threadIdx.x, ch = tid & 127, sub = tid >> 7;
  int cellbase = blockIdx.x * 2;
  int cell = cellbase + sub;
  int n = cnt[SB2 + cell], end = cur[SB2 + cell], start = end - n;
  float acc = __uint_as_float(0xff800000u);
  for (int i = start; i < end; i++) {
    int p = pidx[i];
    acc = fmaxf(acc, f[(size_t)p * 128 + ch]);
  }
  float val = (n > 0) ? acc : 0.f;
  __shared__ float tile[2][128];
  tile[sub][ch] = val;
  __syncthreads();
  int c = tid >> 1, xi = tid & 1;
  int x0 = cellbase & 63, y = (cellbase >> 6) & 63, b = cellbase >> 12;
  out[O_BEV2 + ((((b * 128 + c) * 64 + y) * 64) + x0 + xi)] = tile[xi][c];
}

__global__ __launch_bounds__(256) void k_bevg3(
    const float* __restrict__ f, const int* __restrict__ cnt, const int* __restrict__ cur,
    const int* __restrict__ pidx, float* __restrict__ out)
{
  int tid = threadIdx.x;
  int cellbase = blockIdx.x * 2;
  __shared__ float tile[2][256];
#pragma unroll
  for (int s = 0; s < 2; s++) {
    int cell = cellbase + s;
    int n = cnt[SB3 + cell], end = cur[SB3 + cell], start = end - n;
    float acc = __uint_as_float(0xff800000u);
    for (int i = start; i < end; i++) {
      int p = pidx[i];
      acc = fmaxf(acc, f[(size_t)p * 256 + tid]);
    }
    tile[s][tid] = (n > 0) ? acc : 0.f;
  }
  __syncthreads();
  int x0 = cellbase & 31, y = (cellbase >> 5) & 31, b = cellbase >> 10;
#pragma unroll
  for (int r = 0; r < 2; r++) {
    int c = (tid >> 1) + r * 128, xi = tid & 1;
    out[O_BEV3 + ((((b * 256 + c) * 32 + y) * 32) + x0 + xi)] = tile[xi][c];
  }
}

// ---------------- semantic target ----------------
__global__ __launch_bounds__(256) void k_count(
    const int* __restrict__ i2, const int* __restrict__ i4, const int* __restrict__ i8,
    const int* __restrict__ lab, int* __restrict__ cnt)
{
  int blk = blockIdx.x;
  const int* pc; int Z, Y, X; int* base; int i;
  if (blk < 1954)      { pc = i2; Z = Z_1; Y = Y_1; X = X_1; base = cnt + WC1; i = blk * 256 + threadIdx.x; }
  else if (blk < 3908) { pc = i4; Z = Z_2; Y = Y_2; X = X_2; base = cnt + WC2; i = (blk - 1954) * 256 + threadIdx.x; }
  else                 { pc = i8; Z = Z_3; Y = Y_3; X = X_3; base = cnt + WC3; i = (blk - 3908) * 256 + threadIdx.x; }
  if (i >= 500000) return;
  int b = pc[i * 4], z = pc[i * 4 + 1], y = pc[i * 4 + 2], x = pc[i * 4 + 3];
  int lin = ((b * Z + z) * Y + y) * X + x;
  atomicAdd(base + lin * NLAB + lab[i], 1);
}

__global__ __launch_bounds__(256) void k_lbl(
    const int* __restrict__ fc1, const int* __restrict__ fc2, const int* __restrict__ fc3,
    const int* __restrict__ cnt, float* __restrict__ out)
{
  int blk = blockIdx.x;
  const int* fc; int Z, Y, X, M; const int* base; long lbase; int m;
  if (blk < HB1)            { fc = fc1; Z = Z_1; Y = Y_1; X = X_1; M = M_1; base = cnt + WC1; lbase = O_LBL1; m = blk * 256 + threadIdx.x; }
  else if (blk < HB1 + HB2) { fc = fc2; Z = Z_2; Y = Y_2; X = X_2; M = M_2; base = cnt + WC2; lbase = O_LBL2; m = (blk - HB1) * 256 + threadIdx.x; }
  else                      { fc = fc3; Z = Z_3; Y = Y_3; X = X_3; M = M_3; base = cnt + WC3; lbase = O_LBL3; m = (blk - HB1 - HB2) * 256 + threadIdx.x; }
  if (m >= M) return;
  int b = fc[m * 4], z = fc[m * 4 + 1], y = fc[m * 4 + 2], x = fc[m * 4 + 3];
  int lin = ((b * Z + z) * Y + y) * X + x;
  const int* cp = base + lin * NLAB;
  int best = cp[0]; int bi = 0;
#pragma unroll
  for (int n = 1; n < NLAB; n++) { int cc = cp[n]; if (cc > best) { best = cc; bi = n; } }
  out[lbase + m] = (float)bi;
}

// ---------------- head GEMM (h = x @ w1), transposed col-stat partials ----------------
__global__ __launch_bounds__(256) void k_gemm(
    const float* __restrict__ x1, const float* __restrict__ x2, const float* __restrict__ x3,
    const float* __restrict__ w1a, const float* __restrict__ w1b, const float* __restrict__ w1c,
    __hip_bfloat16* __restrict__ hbuf, float* __restrict__ part)
{
  int blk = blockIdx.x;
  const float* x; const float* w1; __hip_bfloat16* h; float* pp; int Cin, M, bl, NB;
  if (blk < GB1)            { x = x1; w1 = w1a; h = hbuf + WH1; pp = part + WP1; Cin = C_1; M = M_1; bl = blk;             NB = GB1; }
  else if (blk < GB1 + GB2) { x = x2; w1 = w1b; h = hbuf + WH2; pp = part + WP2; Cin = C_2; M = M_2; bl = blk - GB1;       NB = GB2; }
  else                      { x = x3; w1 = w1c; h = hbuf + WH3; pp = part + WP3; Cin = C_3; M = M_3; bl = blk - GB1 - GB2; NB = GB3; }
  int tid = threadIdx.x;
  int lane = tid & 63;
  int wv = __builtin_amdgcn_readfirstlane(tid >> 6);
  int rowbase = bl * 128 + wv * 32;

  float acc[32];
#pragma unroll
  for (int r = 0; r < 32; r++) acc[r] = 0.f;

  int ktiles = Cin >> 5;
  for (int kt = 0; kt < ktiles; kt++) {
    float w1r[32];
#pragma unroll
    for (int k = 0; k < 32; k++) w1r[k] = w1[(kt * 32 + k) * 64 + lane];
#pragma unroll
    for (int r = 0; r < 32; r++) {
      int row = rowbase + r;
      if (row < M) {
        const float* xp = x + (size_t)row * Cin + kt * 32;  // wave-uniform address
#pragma unroll
        for (int k = 0; k < 32; k++) acc[r] = fmaf(xp[k], w1r[k], acc[r]);
      }
    }
  }

  float s = 0.f, ss = 0.f;
#pragma unroll
  for (int r = 0; r < 32; r++) {
    int row = rowbase + r;
    if (row < M) {
      float v = acc[r];
      s += v; ss = fmaf(v, v, ss);
      h[(size_t)row * 64 + lane] = __float2bfloat16(v);
    }
  }
  __shared__ float red[8][64];
  red[wv][lane] = s;
  red[4 + wv][lane] = ss;
  __syncthreads();
  // transposed partials: sum at pp[col*NB + bl], sumsq at pp[(64+col)*NB + bl]
  if (tid < 64) {
    pp[tid * NB + bl] = red[0][tid] + red[1][tid] + red[2][tid] + red[3][tid];
  } else if (tid < 128) {
    int n = tid - 64;
    pp[(64 + n) * NB + bl] = red[4][n] + red[5][n] + red[6][n] + red[7][n];
  }
}

// one block per (scale, column): coalesced contiguous reduction of NB partials
__global__ __launch_bounds__(256) void k_stats(const float* __restrict__ part, float* __restrict__ stats) {
  int blk = blockIdx.x;
  int sc = blk >> 6, col = blk & 63;
  int nb; const float* p; float invM;
  if (sc == 0)      { nb = GB1; p = part + WP1; invM = 1.f / M_1; }
  else if (sc == 1) { nb = GB2; p = part + WP2; invM = 1.f / M_2; }
  else              { nb = GB3; p = part + WP3; invM = 1.f / M_3; }
  int t = threadIdx.x;
  const float* ps = p + (size_t)col * nb;
  const float* pq = p + (size_t)(64 + col) * nb;
  float s = 0.f, q = 0.f;
  for (int i = t; i < nb; i += 256) { s += ps[i]; q += pq[i]; }
  __shared__ float r1[256], r2[256];
  r1[t] = s; r2[t] = q;
  __syncthreads();
  for (int off = 128; off > 0; off >>= 1) {
    if (t < off) { r1[t] += r1[t + off]; r2[t] += r2[t + off]; }
    __syncthreads();
  }
  if (t == 0) {
    float mu  = r1[0] * invM;
    float var = r2[0] * invM - mu * mu;
    stats[sc * 128 + col]      = mu;
    stats[sc * 128 + 64 + col] = rsqrtf(var + 1e-5f);
  }
}

// ---------------- head epilogue: normalize -> leaky -> @ w2 + b2 ----------------
__global__ __launch_bounds__(256) void k_head(
    const u16* __restrict__ hbuf, const float* __restrict__ stats,
    const float* __restrict__ g1, const float* __restrict__ bb1, const float* __restrict__ w21, const float* __restrict__ c21,
    const float* __restrict__ g4, const float* __restrict__ bb4, const float* __restrict__ w24, const float* __restrict__ c24,
    const float* __restrict__ g8, const float* __restrict__ bb8, const float* __restrict__ w28, const float* __restrict__ c28,
    float* __restrict__ out)
{
  int blk = blockIdx.x;
  const u16* h; const float* st; const float* g; const float* bb; const float* w2; const float* b2;
  int M; long obase; int m;
  if (blk < HB1)            { h = hbuf + WH1; st = stats;       g = g1; bb = bb1; w2 = w21; b2 = c21; M = M_1; obase = O_LOG1; m = blk * 256 + threadIdx.x; }
  else if (blk < HB1 + HB2) { h = hbuf + WH2; st = stats + 128; g = g4; bb = bb4; w2 = w24; b2 = c24; M = M_2; obase = O_LOG2; m = (blk - HB1) * 256 + threadIdx.x; }
  else                      { h = hbuf + WH3; st = stats + 256; g = g8; bb = bb8; w2 = w28; b2 = c28; M = M_3; obase = O_LOG3; m = (blk - HB1 - HB2) * 256 + threadIdx.x; }
  if (m >= M) return;
  const uint4* hp = (const uint4*)(h + (size_t)m * 64);
  float acc[19];
#pragma unroll
  for (int n = 0; n < 19; n++) acc[n] = 0.f;
#pragma unroll
  for (int i = 0; i < 8; i++) {
    uint4 q = hp[i];
    u32 uu[4] = { q.x, q.y, q.z, q.w };
#pragma unroll
    for (int t = 0; t < 4; t++) {
      int j = i * 8 + t * 2;
      float f0 = __uint_as_float(uu[t] << 16);
      float f1 = __uint_as_float(uu[t] & 0xffff0000u);
      float a0 = fmaf((f0 - st[j])     * st[64 + j],     g[j],     bb[j]);
      a0 = a0 >= 0.f ? a0 : 0.1f * a0;
      float a1 = fmaf((f1 - st[j + 1]) * st[64 + j + 1], g[j + 1], bb[j + 1]);
      a1 = a1 >= 0.f ? a1 : 0.1f * a1;
#pragma unroll
      for (int n = 0; n < 19; n++) acc[n] = fmaf(a0, w2[j * 19 + n], acc[n]);
#pragma unroll
      for (int n = 0; n < 19; n++) acc[n] = fmaf(a1, w2[(j + 1) * 19 + n], acc[n]);
    }
  }
  float* op = out + obase + (size_t)m * 19;
#pragma unroll
  for (int n = 0; n < 19; n++) op[n] = acc[n] + b2[n];
}

// ---------------- launch ----------------
extern "C" void kernel_launch(void* const* d_in, const int* in_sizes, int n_in,
                              void* d_out, int out_size, void* d_ws, size_t ws_size,
                              hipStream_t stream) {
  (void)in_sizes; (void)n_in; (void)out_size; (void)ws_size;
  const float* p1 = (const float*)d_in[0];
  const float* p2 = (const float*)d_in[1];
  const float* p3 = (const float*)d_in[2];
  const int* vc1  = (const int*)d_in[3];
  const int* vc2  = (const int*)d_in[4];
  const int* vc3  = (const int*)d_in[5];
  const int* i2   = (const int*)d_in[6];
  const int* i4   = (const int*)d_in[7];
  const int* i8   = (const int*)d_in[8];
  const int* lab  = (const int*)d_in[9];
  const float* h2w1 = (const float*)d_in[10]; const float* h2g = (const float*)d_in[11];
  const float* h2b  = (const float*)d_in[12]; const float* h2w2 = (const float*)d_in[13];
  const float* h2b2 = (const float*)d_in[14];
  const float* h4w1 = (const float*)d_in[15]; const float* h4g = (const float*)d_in[16];
  const float* h4b  = (const float*)d_in[17]; const float* h4w2 = (const float*)d_in[18];
  const float* h4b2 = (const float*)d_in[19];
  const float* h8w1 = (const float*)d_in[20]; const float* h8g = (const float*)d_in[21];
  const float* h8b  = (const float*)d_in[22]; const float* h8w2 = (const float*)d_in[23];
  const float* h8b2 = (const float*)d_in[24];

  float* out = (float*)d_out;
  int* wsi = (int*)d_ws;
  float* wsf = (float*)d_ws;
  __hip_bfloat16* wsh = (__hip_bfloat16*)d_ws;

  // ---- BEV: counting-sort + gather (no global atomic-max) ----
  hipMemsetAsync(wsi + WB_CNT, 0, NCELLS * sizeof(int), stream);
  k_cellcount<<<HB1 + HB2 + HB3, 256, 0, stream>>>(vc1, vc2, vc3, wsi + WB_CNT);
  k_scan<<<1, 1024, 0, stream>>>(wsi + WB_CNT, wsi + WB_CUR);
  k_scatter<<<HB1 + HB2 + HB3, 256, 0, stream>>>(vc1, vc2, vc3, wsi + WB_CUR, wsi + WB_PIDX);
  k_bevg1<<<8192, 256, 0, stream>>>(p1, wsi + WB_CNT, wsi + WB_CUR, wsi + WB_PIDX, out);
  k_bevg2<<<4096, 256, 0, stream>>>(p2, wsi + WB_CNT, wsi + WB_CUR, wsi + WB_PIDX, out);
  k_bevg3<<<1024, 256, 0, stream>>>(p3, wsi + WB_CNT, wsi + WB_CUR, wsi + WB_PIDX, out);

  // ---- semantic targets (reuses ws bytes; stream-ordered after BEV) ----
  hipMemsetAsync(d_ws, 0, W_COUNT_BYTES, stream);
  k_count<<<5862, 256, 0, stream>>>(i2, i4, i8, lab, wsi);
  k_lbl<<<HB1 + HB2 + HB3, 256, 0, stream>>>(vc1, vc2, vc3, wsi, out);

  // ---- heads (h reuses the counts bytes; counts fully consumed by k_lbl) ----
  k_gemm<<<GB1 + GB2 + GB3, 256, 0, stream>>>(p1, p2, p3, h2w1, h4w1, h8w1, wsh, wsf + WPART);
  k_stats<<<192, 256, 0, stream>>>(wsf + WPART, wsf + WSTATS);
  k_head<<<HB1 + HB2 + HB3, 256, 0, stream>>>((const u16*)d_ws, wsf + WSTATS,
      h2g, h2b, h2w2, h2b2, h4g, h4b, h4w2, h4b2, h8g, h8b, h8w2, h8b2, out);
}

// Round 4
// 536.208 us; speedup vs baseline: 4.2146x; 1.3034x over previous
//
#include <hip/hip_runtime.h>
#include <hip/hip_bf16.h>

typedef unsigned int u32;
typedef unsigned short u16;
typedef __attribute__((ext_vector_type(8))) short short8;
typedef __attribute__((ext_vector_type(4))) float f32x4;

// ---------------- problem constants ----------------
#define NLAB 20

#define M_1 200000
#define C_1 64
#define Z_1 16
#define Y_1 128
#define X_1 128

#define M_2 100000
#define C_2 128
#define Z_2 8
#define Y_2 64
#define X_2 64

#define M_3 50000
#define C_3 256
#define Z_3 4
#define Y_3 32
#define X_3 32

// output float offsets (concatenated in reference return order)
#define O_BEV1 0
#define O_BEV2 2097152
#define O_BEV3 3145728
#define O_LOG1 3670016
#define O_LOG2 7470016
#define O_LOG3 9370016
#define O_LBL1 10320016
#define O_LBL2 10520016
#define O_LBL3 10620016

// ---------------- ws layout (phase-reused, stream-ordered) ----------------
#define WB_CNT 0
#define WB_CUR 43008
#define WB_PIDX 86016
#define NCELLS 43008
#define SB1 0
#define SB2 32768
#define SB3 40960

#define WC1 0
#define WC2 10485760
#define WC3 11796480
#define W_COUNT_BYTES 47841280ull
// bf16 (u16) element offsets for h
#define WH1 0
#define WH2 12800000
#define WH3 19200000
// float element offsets (partials transposed: sum[col*NB+bl], ss at (64+col)*NB+bl)
#define WPART 12000000
#define WP1 0
#define WP2 200064
#define WP3 300160
#define WSTATS 12350208

// gemm: 128 rows per block
#define GB1 1563
#define GB2 782
#define GB3 391
// head/lbl/point-loop: 256 rows per block
#define HB1 782
#define HB2 391
#define HB3 196

static __device__ __forceinline__ u16 f2bf(float f) {
  u32 u = __float_as_uint(f);
  u32 r = u + 0x7fffu + ((u >> 16) & 1u);   // RNE; inputs finite
  return (u16)(r >> 16);
}

// ---------------- BEV phase A: count points per cell ----------------
__global__ __launch_bounds__(256) void k_cellcount(
    const int* __restrict__ co1, const int* __restrict__ co2, const int* __restrict__ co3,
    int* __restrict__ cnt)
{
  int blk = blockIdx.x;
  const int* co; int Y, X, M, base, m;
  if (blk < HB1)            { co = co1; Y = Y_1; X = X_1; M = M_1; base = SB1; m = blk * 256 + threadIdx.x; }
  else if (blk < HB1 + HB2) { co = co2; Y = Y_2; X = X_2; M = M_2; base = SB2; m = (blk - HB1) * 256 + threadIdx.x; }
  else                      { co = co3; Y = Y_3; X = X_3; M = M_3; base = SB3; m = (blk - HB1 - HB2) * 256 + threadIdx.x; }
  if (m >= M) return;
  int b = co[m * 4], y = co[m * 4 + 2], x = co[m * 4 + 3];
  atomicAdd(cnt + base + (b * Y + y) * X + x, 1);
}

// ---------------- BEV phase B: exclusive prefix scan over all cells ----------------
__global__ __launch_bounds__(1024) void k_scan(const int* __restrict__ cnt, int* __restrict__ cur) {
  int t = threadIdx.x;            // 1024 threads, 42 cells each = 43008
  int local[42];
  int s = 0;
#pragma unroll
  for (int j = 0; j < 42; j++) { local[j] = cnt[t * 42 + j]; s += local[j]; }
  __shared__ int red[1024];
  red[t] = s;
  __syncthreads();
  for (int off = 1; off < 1024; off <<= 1) {
    int v = (t >= off) ? red[t - off] : 0;
    __syncthreads();
    red[t] += v;
    __syncthreads();
  }
  int base = red[t] - s;
#pragma unroll
  for (int j = 0; j < 42; j++) { cur[t * 42 + j] = base; base += local[j]; }
}

// ---------------- BEV phase C: scatter point indices into sorted order ----------------
__global__ __launch_bounds__(256) void k_scatter(
    const int* __restrict__ co1, const int* __restrict__ co2, const int* __restrict__ co3,
    int* __restrict__ cur, int* __restrict__ pidx)
{
  int blk = blockIdx.x;
  const int* co; int Y, X, M, base, m;
  if (blk < HB1)            { co = co1; Y = Y_1; X = X_1; M = M_1; base = SB1; m = blk * 256 + threadIdx.x; }
  else if (blk < HB1 + HB2) { co = co2; Y = Y_2; X = X_2; M = M_2; base = SB2; m = (blk - HB1) * 256 + threadIdx.x; }
  else                      { co = co3; Y = Y_3; X = X_3; M = M_3; base = SB3; m = (blk - HB1 - HB2) * 256 + threadIdx.x; }
  if (m >= M) return;
  int b = co[m * 4], y = co[m * 4 + 2], x = co[m * 4 + 3];
  int slot = atomicAdd(cur + base + (b * Y + y) * X + x, 1);
  pidx[slot] = m;
}

// ---------------- BEV phase D: gather-max per cell ----------------
__global__ __launch_bounds__(256) void k_bevg1(
    const float* __restrict__ f, const int* __restrict__ cnt, const int* __restrict__ cur,
    const int* __restrict__ pidx, float* __restrict__ out)
{
  int tid = threadIdx.x, lane = tid & 63, wv = tid >> 6;
  int cellbase = blockIdx.x * 4;
  int cell = cellbase + wv;
  int n = cnt[SB1 + cell], end = cur[SB1 + cell], start = end - n;
  float acc = __uint_as_float(0xff800000u);
  for (int i = start; i < end; i++) {
    int p = pidx[i];
    acc = fmaxf(acc, f[(size_t)p * 64 + lane]);
  }
  float val = (n > 0) ? acc : 0.f;
  __shared__ float tile[4][72];
  tile[wv][lane] = val;
  __syncthreads();
  int c = tid >> 2, xi = tid & 3;
  int x0 = cellbase & 127, y = (cellbase >> 7) & 127, b = cellbase >> 14;
  out[O_BEV1 + ((((b * 64 + c) * 128 + y) * 128) + x0 + xi)] = tile[xi][c];
}

__global__ __launch_bounds__(256) void k_bevg2(
    const float* __restrict__ f, const int* __restrict__ cnt, const int* __restrict__ cur,
    const int* __restrict__ pidx, float* __restrict__ out)
{
  int tid = threadIdx.x, ch = tid & 127, sub = tid >> 7;
  int cellbase = blockIdx.x * 2;
  int cell = cellbase + sub;
  int n = cnt[SB2 + cell], end = cur[SB2 + cell], start = end - n;
  float acc = __uint_as_float(0xff800000u);
  for (int i = start; i < end; i++) {
    int p = pidx[i];
    acc = fmaxf(acc, f[(size_t)p * 128 + ch]);
  }
  float val = (n > 0) ? acc : 0.f;
  __shared__ float tile[2][128];
  tile[sub][ch] = val;
  __syncthreads();
  int c = tid >> 1, xi = tid & 1;
  int x0 = cellbase & 63, y = (cellbase >> 6) & 63, b = cellbase >> 12;
  out[O_BEV2 + ((((b * 128 + c) * 64 + y) * 64) + x0 + xi)] = tile[xi][c];
}

__global__ __launch_bounds__(256) void k_bevg3(
    const float* __restrict__ f, const int* __restrict__ cnt, const int* __restrict__ cur,
    const int* __restrict__ pidx, float* __restrict__ out)
{
  int tid = threadIdx.x;
  int cellbase = blockIdx.x * 2;
  __shared__ float tile[2][256];
#pragma unroll
  for (int s = 0; s < 2; s++) {
    int cell = cellbase + s;
    int n = cnt[SB3 + cell], end = cur[SB3 + cell], start = end - n;
    float acc = __uint_as_float(0xff800000u);
    for (int i = start; i < end; i++) {
      int p = pidx[i];
      acc = fmaxf(acc, f[(size_t)p * 256 + tid]);
    }
    tile[s][tid] = (n > 0) ? acc : 0.f;
  }
  __syncthreads();
  int x0 = cellbase & 31, y = (cellbase >> 5) & 31, b = cellbase >> 10;
#pragma unroll
  for (int r = 0; r < 2; r++) {
    int c = (tid >> 1) + r * 128, xi = tid & 1;
    out[O_BEV3 + ((((b * 256 + c) * 32 + y) * 32) + x0 + xi)] = tile[xi][c];
  }
}

// ---------------- semantic target ----------------
__global__ __launch_bounds__(256) void k_count(
    const int* __restrict__ i2, const int* __restrict__ i4, const int* __restrict__ i8,
    const int* __restrict__ lab, int* __restrict__ cnt)
{
  int blk = blockIdx.x;
  const int* pc; int Z, Y, X; int* base; int i;
  if (blk < 1954)      { pc = i2; Z = Z_1; Y = Y_1; X = X_1; base = cnt + WC1; i = blk * 256 + threadIdx.x; }
  else if (blk < 3908) { pc = i4; Z = Z_2; Y = Y_2; X = X_2; base = cnt + WC2; i = (blk - 1954) * 256 + threadIdx.x; }
  else                 { pc = i8; Z = Z_3; Y = Y_3; X = X_3; base = cnt + WC3; i = (blk - 3908) * 256 + threadIdx.x; }
  if (i >= 500000) return;
  int b = pc[i * 4], z = pc[i * 4 + 1], y = pc[i * 4 + 2], x = pc[i * 4 + 3];
  int lin = ((b * Z + z) * Y + y) * X + x;
  atomicAdd(base + lin * NLAB + lab[i], 1);
}

__global__ __launch_bounds__(256) void k_lbl(
    const int* __restrict__ fc1, const int* __restrict__ fc2, const int* __restrict__ fc3,
    const int* __restrict__ cnt, float* __restrict__ out)
{
  int blk = blockIdx.x;
  const int* fc; int Z, Y, X, M; const int* base; long lbase; int m;
  if (blk < HB1)            { fc = fc1; Z = Z_1; Y = Y_1; X = X_1; M = M_1; base = cnt + WC1; lbase = O_LBL1; m = blk * 256 + threadIdx.x; }
  else if (blk < HB1 + HB2) { fc = fc2; Z = Z_2; Y = Y_2; X = X_2; M = M_2; base = cnt + WC2; lbase = O_LBL2; m = (blk - HB1) * 256 + threadIdx.x; }
  else                      { fc = fc3; Z = Z_3; Y = Y_3; X = X_3; M = M_3; base = cnt + WC3; lbase = O_LBL3; m = (blk - HB1 - HB2) * 256 + threadIdx.x; }
  if (m >= M) return;
  int b = fc[m * 4], z = fc[m * 4 + 1], y = fc[m * 4 + 2], x = fc[m * 4 + 3];
  int lin = ((b * Z + z) * Y + y) * X + x;
  const int* cp = base + lin * NLAB;
  int best = cp[0]; int bi = 0;
#pragma unroll
  for (int n = 1; n < NLAB; n++) { int cc = cp[n]; if (cc > best) { best = cc; bi = n; } }
  out[lbase + m] = (float)bi;
}

// ---------------- head GEMM: h = bf16(x) @ bf16(w1) via MFMA 16x16x32 ----------------
// block = 256 thr = 4 waves; tile 128 rows x 64 cols; K-chunks of 64 staged in LDS.
// A LDS: [128][72] u16 (row-major, +8 pad); B LDS: [64][72] u16, n-major (transposed).
// frag layouts (measured, m89/m118): A/B lane&15 = m/n, (lane>>4)*8+j = k;
// C/D: col = lane&15, row = (lane>>4)*4 + reg.
__global__ __launch_bounds__(256) void k_gemm(
    const float* __restrict__ x1, const float* __restrict__ x2, const float* __restrict__ x3,
    const float* __restrict__ w1a, const float* __restrict__ w1b, const float* __restrict__ w1c,
    u16* __restrict__ hbuf, float* __restrict__ part)
{
  int blk = blockIdx.x;
  const float* x; const float* w1; u16* h; float* pp; int Cin, M, bl, NB;
  if (blk < GB1)            { x = x1; w1 = w1a; h = hbuf + WH1; pp = part + WP1; Cin = C_1; M = M_1; bl = blk;             NB = GB1; }
  else if (blk < GB1 + GB2) { x = x2; w1 = w1b; h = hbuf + WH2; pp = part + WP2; Cin = C_2; M = M_2; bl = blk - GB1;       NB = GB2; }
  else                      { x = x3; w1 = w1c; h = hbuf + WH3; pp = part + WP3; Cin = C_3; M = M_3; bl = blk - GB1 - GB2; NB = GB3; }
  int tid = threadIdx.x;
  int lane = tid & 63, wv = tid >> 6;
  int m16 = lane & 15, quad = lane >> 4;

  __shared__ u16 As[128 * 72];
  __shared__ u16 Bs[64 * 72];
  __shared__ float redS[4][64];
  __shared__ float redQ[4][64];

  f32x4 acc[2][4];
#pragma unroll
  for (int mt = 0; mt < 2; mt++)
#pragma unroll
    for (int nt = 0; nt < 4; nt++) acc[mt][nt] = (f32x4){0.f, 0.f, 0.f, 0.f};

  int nchunk = Cin >> 6;
  for (int c = 0; c < nchunk; c++) {
    if (c) __syncthreads();   // previous chunk's LDS reads complete before restage
    // ---- stage A: 128 rows x 64 k (f32 -> bf16) ----
#pragma unroll
    for (int pass = 0; pass < 8; pass++) {
      int fidx = pass * 256 + tid;
      int row = fidx >> 4, kp = (fidx & 15) * 4;
      int grow = bl * 128 + row;
      float4 v = make_float4(0.f, 0.f, 0.f, 0.f);
      if (grow < M) v = *(const float4*)(x + (size_t)grow * Cin + c * 64 + kp);
      ushort4 o = { f2bf(v.x), f2bf(v.y), f2bf(v.z), f2bf(v.w) };
      *(ushort4*)(As + row * 72 + kp) = o;
    }
    // ---- stage B transposed: Bs[n][k] ----
    {
      int n = tid & 63, kg = tid >> 6;
#pragma unroll
      for (int p = 0; p < 4; p++) {
        int k0 = kg * 4 + p * 16;
        const float* wp = w1 + (size_t)(c * 64 + k0) * 64 + n;
        ushort4 o = { f2bf(wp[0]), f2bf(wp[64]), f2bf(wp[128]), f2bf(wp[192]) };
        *(ushort4*)(Bs + n * 72 + k0) = o;
      }
    }
    __syncthreads();
    // ---- MFMA: 2 K-steps of 32 ----
#pragma unroll
    for (int ks = 0; ks < 2; ks++) {
      short8 a0 = *(const short8*)(As + (wv * 32 + m16) * 72 + ks * 32 + quad * 8);
      short8 a1 = *(const short8*)(As + (wv * 32 + 16 + m16) * 72 + ks * 32 + quad * 8);
      short8 b[4];
#pragma unroll
      for (int nt = 0; nt < 4; nt++)
        b[nt] = *(const short8*)(Bs + (nt * 16 + m16) * 72 + ks * 32 + quad * 8);
#pragma unroll
      for (int nt = 0; nt < 4; nt++) {
        acc[0][nt] = __builtin_amdgcn_mfma_f32_16x16x32_bf16(a0, b[nt], acc[0][nt], 0, 0, 0);
        acc[1][nt] = __builtin_amdgcn_mfma_f32_16x16x32_bf16(a1, b[nt], acc[1][nt], 0, 0, 0);
      }
    }
  }

  // ---- epilogue: store h (bf16) + column sum/sumsq partials ----
  float s[4] = {0.f, 0.f, 0.f, 0.f}, q[4] = {0.f, 0.f, 0.f, 0.f};
#pragma unroll
  for (int mt = 0; mt < 2; mt++) {
#pragma unroll
    for (int nt = 0; nt < 4; nt++) {
#pragma unroll
      for (int r = 0; r < 4; r++) {
        float v = acc[mt][nt][r];
        int grow = bl * 128 + wv * 32 + mt * 16 + quad * 4 + r;
        if (grow < M) h[(size_t)grow * 64 + nt * 16 + m16] = f2bf(v);
        s[nt] += v;
        q[nt] = fmaf(v, v, q[nt]);   // OOB rows have v == 0 (A zero-padded)
      }
    }
  }
#pragma unroll
  for (int nt = 0; nt < 4; nt++) {
    s[nt] += __shfl_xor(s[nt], 16); s[nt] += __shfl_xor(s[nt], 32);
    q[nt] += __shfl_xor(q[nt], 16); q[nt] += __shfl_xor(q[nt], 32);
  }
  if (lane < 16) {
#pragma unroll
    for (int nt = 0; nt < 4; nt++) {
      redS[wv][nt * 16 + lane] = s[nt];
      redQ[wv][nt * 16 + lane] = q[nt];
    }
  }
  __syncthreads();
  if (tid < 64) {
    pp[tid * NB + bl] = redS[0][tid] + redS[1][tid] + redS[2][tid] + redS[3][tid];
  } else if (tid < 128) {
    int n2 = tid - 64;
    pp[(64 + n2) * NB + bl] = redQ[0][n2] + redQ[1][n2] + redQ[2][n2] + redQ[3][n2];
  }
}

// one block per (scale, column): coalesced contiguous reduction of NB partials
__global__ __launch_bounds__(256) void k_stats(const float* __restrict__ part, float* __restrict__ stats) {
  int blk = blockIdx.x;
  int sc = blk >> 6, col = blk & 63;
  int nb; const float* p; float invM;
  if (sc == 0)      { nb = GB1; p = part + WP1; invM = 1.f / M_1; }
  else if (sc == 1) { nb = GB2; p = part + WP2; invM = 1.f / M_2; }
  else              { nb = GB3; p = part + WP3; invM = 1.f / M_3; }
  int t = threadIdx.x;
  const float* ps = p + (size_t)col * nb;
  const float* pq = p + (size_t)(64 + col) * nb;
  float s = 0.f, q = 0.f;
  for (int i = t; i < nb; i += 256) { s += ps[i]; q += pq[i]; }
  __shared__ float r1[256], r2[256];
  r1[t] = s; r2[t] = q;
  __syncthreads();
  for (int off = 128; off > 0; off >>= 1) {
    if (t < off) { r1[t] += r1[t + off]; r2[t] += r2[t + off]; }
    __syncthreads();
  }
  if (t == 0) {
    float mu  = r1[0] * invM;
    float var = r2[0] * invM - mu * mu;
    stats[sc * 128 + col]      = mu;
    stats[sc * 128 + 64 + col] = rsqrtf(var + 1e-5f);
  }
}

// ---------------- head epilogue: normalize -> leaky -> @ w2 + b2 ----------------
__global__ __launch_bounds__(256) void k_head(
    const u16* __restrict__ hbuf, const float* __restrict__ stats,
    const float* __restrict__ g1, const float* __restrict__ bb1, const float* __restrict__ w21, const float* __restrict__ c21,
    const float* __restrict__ g4, const float* __restrict__ bb4, const float* __restrict__ w24, const float* __restrict__ c24,
    const float* __restrict__ g8, const float* __restrict__ bb8, const float* __restrict__ w28, const float* __restrict__ c28,
    float* __restrict__ out)
{
  int blk = blockIdx.x;
  const u16* h; const float* st; const float* g; const float* bb; const float* w2; const float* b2;
  int M; long obase; int m;
  if (blk < HB1)            { h = hbuf + WH1; st = stats;       g = g1; bb = bb1; w2 = w21; b2 = c21; M = M_1; obase = O_LOG1; m = blk * 256 + threadIdx.x; }
  else if (blk < HB1 + HB2) { h = hbuf + WH2; st = stats + 128; g = g4; bb = bb4; w2 = w24; b2 = c24; M = M_2; obase = O_LOG2; m = (blk - HB1) * 256 + threadIdx.x; }
  else                      { h = hbuf + WH3; st = stats + 256; g = g8; bb = bb8; w2 = w28; b2 = c28; M = M_3; obase = O_LOG3; m = (blk - HB1 - HB2) * 256 + threadIdx.x; }
  if (m >= M) return;
  const uint4* hp = (const uint4*)(h + (size_t)m * 64);
  float acc[19];
#pragma unroll
  for (int n = 0; n < 19; n++) acc[n] = 0.f;
#pragma unroll
  for (int i = 0; i < 8; i++) {
    uint4 qv = hp[i];
    u32 uu[4] = { qv.x, qv.y, qv.z, qv.w };
#pragma unroll
    for (int t = 0; t < 4; t++) {
      int j = i * 8 + t * 2;
      float f0 = __uint_as_float(uu[t] << 16);
      float f1 = __uint_as_float(uu[t] & 0xffff0000u);
      float a0 = fmaf((f0 - st[j])     * st[64 + j],     g[j],     bb[j]);
      a0 = a0 >= 0.f ? a0 : 0.1f * a0;
      float a1 = fmaf((f1 - st[j + 1]) * st[64 + j + 1], g[j + 1], bb[j + 1]);
      a1 = a1 >= 0.f ? a1 : 0.1f * a1;
#pragma unroll
      for (int n = 0; n < 19; n++) acc[n] = fmaf(a0, w2[j * 19 + n], acc[n]);
#pragma unroll
      for (int n = 0; n < 19; n++) acc[n] = fmaf(a1, w2[(j + 1) * 19 + n], acc[n]);
    }
  }
  float* op = out + obase + (size_t)m * 19;
#pragma unroll
  for (int n = 0; n < 19; n++) op[n] = acc[n] + b2[n];
}

// ---------------- launch ----------------
extern "C" void kernel_launch(void* const* d_in, const int* in_sizes, int n_in,
                              void* d_out, int out_size, void* d_ws, size_t ws_size,
                              hipStream_t stream) {
  (void)in_sizes; (void)n_in; (void)out_size; (void)ws_size;
  const float* p1 = (const float*)d_in[0];
  const float* p2 = (const float*)d_in[1];
  const float* p3 = (const float*)d_in[2];
  const int* vc1  = (const int*)d_in[3];
  const int* vc2  = (const int*)d_in[4];
  const int* vc3  = (const int*)d_in[5];
  const int* i2   = (const int*)d_in[6];
  const int* i4   = (const int*)d_in[7];
  const int* i8   = (const int*)d_in[8];
  const int* lab  = (const int*)d_in[9];
  const float* h2w1 = (const float*)d_in[10]; const float* h2g = (const float*)d_in[11];
  const float* h2b  = (const float*)d_in[12]; const float* h2w2 = (const float*)d_in[13];
  const float* h2b2 = (const float*)d_in[14];
  const float* h4w1 = (const float*)d_in[15]; const float* h4g = (const float*)d_in[16];
  const float* h4b  = (const float*)d_in[17]; const float* h4w2 = (const float*)d_in[18];
  const float* h4b2 = (const float*)d_in[19];
  const float* h8w1 = (const float*)d_in[20]; const float* h8g = (const float*)d_in[21];
  const float* h8b  = (const float*)d_in[22]; const float* h8w2 = (const float*)d_in[23];
  const float* h8b2 = (const float*)d_in[24];

  float* out = (float*)d_out;
  int* wsi = (int*)d_ws;
  float* wsf = (float*)d_ws;
  u16* wsh = (u16*)d_ws;

  // ---- BEV: counting-sort + gather (no global atomic-max) ----
  hipMemsetAsync(wsi + WB_CNT, 0, NCELLS * sizeof(int), stream);
  k_cellcount<<<HB1 + HB2 + HB3, 256, 0, stream>>>(vc1, vc2, vc3, wsi + WB_CNT);
  k_scan<<<1, 1024, 0, stream>>>(wsi + WB_CNT, wsi + WB_CUR);
  k_scatter<<<HB1 + HB2 + HB3, 256, 0, stream>>>(vc1, vc2, vc3, wsi + WB_CUR, wsi + WB_PIDX);
  k_bevg1<<<8192, 256, 0, stream>>>(p1, wsi + WB_CNT, wsi + WB_CUR, wsi + WB_PIDX, out);
  k_bevg2<<<4096, 256, 0, stream>>>(p2, wsi + WB_CNT, wsi + WB_CUR, wsi + WB_PIDX, out);
  k_bevg3<<<1024, 256, 0, stream>>>(p3, wsi + WB_CNT, wsi + WB_CUR, wsi + WB_PIDX, out);

  // ---- semantic targets (reuses ws bytes; stream-ordered after BEV) ----
  hipMemsetAsync(d_ws, 0, W_COUNT_BYTES, stream);
  k_count<<<5862, 256, 0, stream>>>(i2, i4, i8, lab, wsi);
  k_lbl<<<HB1 + HB2 + HB3, 256, 0, stream>>>(vc1, vc2, vc3, wsi, out);

  // ---- heads (h reuses the counts bytes; counts fully consumed by k_lbl) ----
  k_gemm<<<GB1 + GB2 + GB3, 256, 0, stream>>>(p1, p2, p3, h2w1, h4w1, h8w1, wsh, wsf + WPART);
  k_stats<<<192, 256, 0, stream>>>(wsf + WPART, wsf + WSTATS);
  k_head<<<HB1 + HB2 + HB3, 256, 0, stream>>>((const u16*)d_ws, wsf + WSTATS,
      h2g, h2b, h2w2, h2b2, h4g, h4b, h4w2, h4b2, h8g, h8b, h8w2, h8b2, out);
}

// Round 6
// 523.534 us; speedup vs baseline: 4.3167x; 1.0242x over previous
//
#include <hip/hip_runtime.h>
#include <hip/hip_bf16.h>

typedef unsigned int u32;
typedef unsigned short u16;
typedef __attribute__((ext_vector_type(8))) short short8;
typedef __attribute__((ext_vector_type(4))) float f32x4;

// ---------------- problem constants ----------------
#define NLAB 20

#define M_1 200000
#define C_1 64
#define Z_1 16
#define Y_1 128
#define X_1 128

#define M_2 100000
#define C_2 128
#define Z_2 8
#define Y_2 64
#define X_2 64

#define M_3 50000
#define C_3 256
#define Z_3 4
#define Y_3 32
#define X_3 32

// output float offsets (concatenated in reference return order)
#define O_BEV1 0
#define O_BEV2 2097152
#define O_BEV3 3145728
#define O_LOG1 3670016
#define O_LOG2 7470016
#define O_LOG3 9370016
#define O_LBL1 10320016
#define O_LBL2 10520016
#define O_LBL3 10620016

// ---------------- ws layout (phase-reused, stream-ordered) ----------------
#define WB_CNT 0
#define WB_CUR 43008
#define WB_PIDX 86016
#define NCELLS 43008
#define SB1 0
#define SB2 32768
#define SB3 40960

#define WC1 0
#define WC2 10485760
#define WC3 11796480
#define W_COUNT_BYTES 47841280ull
// bf16 (u16) element offsets for h
#define WH1 0
#define WH2 12800000
#define WH3 19200000
// float element offsets (partials transposed: sum[col*NB+bl], ss at (64+col)*NB+bl)
#define WPART 12000000
#define WP1 0
#define WP2 200064
#define WP3 300160
#define WSTATS 12350208

// gemm: 128 rows per block
#define GB1 1563
#define GB2 782
#define GB3 391
// head/lbl/point-loop: 256 rows per block
#define HB1 782
#define HB2 391
#define HB3 196

static __device__ __forceinline__ u16 f2bf(float f) {
  u32 u = __float_as_uint(f);
  u32 r = u + 0x7fffu + ((u >> 16) & 1u);   // RNE; inputs finite
  return (u16)(r >> 16);
}

// ---------------- BEV phase A: count points per cell ----------------
__global__ __launch_bounds__(256) void k_cellcount(
    const int* __restrict__ co1, const int* __restrict__ co2, const int* __restrict__ co3,
    int* __restrict__ cnt)
{
  int blk = blockIdx.x;
  const int* co; int Y, X, M, base, m;
  if (blk < HB1)            { co = co1; Y = Y_1; X = X_1; M = M_1; base = SB1; m = blk * 256 + threadIdx.x; }
  else if (blk < HB1 + HB2) { co = co2; Y = Y_2; X = X_2; M = M_2; base = SB2; m = (blk - HB1) * 256 + threadIdx.x; }
  else                      { co = co3; Y = Y_3; X = X_3; M = M_3; base = SB3; m = (blk - HB1 - HB2) * 256 + threadIdx.x; }
  if (m >= M) return;
  int b = co[m * 4], y = co[m * 4 + 2], x = co[m * 4 + 3];
  atomicAdd(cnt + base + (b * Y + y) * X + x, 1);
}

// ---------------- BEV phase B: exclusive prefix scan over all cells ----------------
__global__ __launch_bounds__(1024) void k_scan(const int* __restrict__ cnt, int* __restrict__ cur) {
  int t = threadIdx.x;            // 1024 threads, 42 cells each = 43008
  int local[42];
  int s = 0;
#pragma unroll
  for (int j = 0; j < 42; j++) { local[j] = cnt[t * 42 + j]; s += local[j]; }
  __shared__ int red[1024];
  red[t] = s;
  __syncthreads();
  for (int off = 1; off < 1024; off <<= 1) {
    int v = (t >= off) ? red[t - off] : 0;
    __syncthreads();
    red[t] += v;
    __syncthreads();
  }
  int base = red[t] - s;
#pragma unroll
  for (int j = 0; j < 42; j++) { cur[t * 42 + j] = base; base += local[j]; }
}

// ---------------- BEV phase C: scatter point indices into sorted order ----------------
__global__ __launch_bounds__(256) void k_scatter(
    const int* __restrict__ co1, const int* __restrict__ co2, const int* __restrict__ co3,
    int* __restrict__ cur, int* __restrict__ pidx)
{
  int blk = blockIdx.x;
  const int* co; int Y, X, M, base, m;
  if (blk < HB1)            { co = co1; Y = Y_1; X = X_1; M = M_1; base = SB1; m = blk * 256 + threadIdx.x; }
  else if (blk < HB1 + HB2) { co = co2; Y = Y_2; X = X_2; M = M_2; base = SB2; m = (blk - HB1) * 256 + threadIdx.x; }
  else                      { co = co3; Y = Y_3; X = X_3; M = M_3; base = SB3; m = (blk - HB1 - HB2) * 256 + threadIdx.x; }
  if (m >= M) return;
  int b = co[m * 4], y = co[m * 4 + 2], x = co[m * 4 + 3];
  int slot = atomicAdd(cur + base + (b * Y + y) * X + x, 1);
  pidx[slot] = m;
}

// ---------------- BEV phase D: gather-max per cell ----------------
__global__ __launch_bounds__(256) void k_bevg1(
    const float* __restrict__ f, const int* __restrict__ cnt, const int* __restrict__ cur,
    const int* __restrict__ pidx, float* __restrict__ out)
{
  int tid = threadIdx.x, lane = tid & 63, wv = tid >> 6;
  int cellbase = blockIdx.x * 4;
  int cell = cellbase + wv;
  int n = cnt[SB1 + cell], end = cur[SB1 + cell], start = end - n;
  float acc = __uint_as_float(0xff800000u);
  for (int i = start; i < end; i++) {
    int p = pidx[i];
    acc = fmaxf(acc, f[(size_t)p * 64 + lane]);
  }
  float val = (n > 0) ? acc : 0.f;
  __shared__ float tile[4][72];
  tile[wv][lane] = val;
  __syncthreads();
  int c = tid >> 2, xi = tid & 3;
  int x0 = cellbase & 127, y = (cellbase >> 7) & 127, b = cellbase >> 14;
  out[O_BEV1 + ((((b * 64 + c) * 128 + y) * 128) + x0 + xi)] = tile[xi][c];
}

__global__ __launch_bounds__(256) void k_bevg2(
    const float* __restrict__ f, const int* __restrict__ cnt, const int* __restrict__ cur,
    const int* __restrict__ pidx, float* __restrict__ out)
{
  int tid = threadIdx.x, ch = tid & 127, sub = tid >> 7;
  int cellbase = blockIdx.x * 2;
  int cell = cellbase + sub;
  int n = cnt[SB2 + cell], end = cur[SB2 + cell], start = end - n;
  float acc = __uint_as_float(0xff800000u);
  for (int i = start; i < end; i++) {
    int p = pidx[i];
    acc = fmaxf(acc, f[(size_t)p * 128 + ch]);
  }
  float val = (n > 0) ? acc : 0.f;
  __shared__ float tile[2][128];
  tile[sub][ch] = val;
  __syncthreads();
  int c = tid >> 1, xi = tid & 1;
  int x0 = cellbase & 63, y = (cellbase >> 6) & 63, b = cellbase >> 12;
  out[O_BEV2 + ((((b * 128 + c) * 64 + y) * 64) + x0 + xi)] = tile[xi][c];
}

__global__ __launch_bounds__(256) void k_bevg3(
    const float* __restrict__ f, const int* __restrict__ cnt, const int* __restrict__ cur,
    const int* __restrict__ pidx, float* __restrict__ out)
{
  int tid = threadIdx.x;
  int cellbase = blockIdx.x * 2;
  __shared__ float tile[2][256];
#pragma unroll
  for (int s = 0; s < 2; s++) {
    int cell = cellbase + s;
    int n = cnt[SB3 + cell], end = cur[SB3 + cell], start = end - n;
    float acc = __uint_as_float(0xff800000u);
    for (int i = start; i < end; i++) {
      int p = pidx[i];
      acc = fmaxf(acc, f[(size_t)p * 256 + tid]);
    }
    tile[s][tid] = (n > 0) ? acc : 0.f;
  }
  __syncthreads();
  int x0 = cellbase & 31, y = (cellbase >> 5) & 31, b = cellbase >> 10;
#pragma unroll
  for (int r = 0; r < 2; r++) {
    int c = (tid >> 1) + r * 128, xi = tid & 1;
    out[O_BEV3 + ((((b * 256 + c) * 32 + y) * 32) + x0 + xi)] = tile[xi][c];
  }
}

// ---------------- semantic target ----------------
__global__ __launch_bounds__(256) void k_count(
    const int* __restrict__ i2, const int* __restrict__ i4, const int* __restrict__ i8,
    const int* __restrict__ lab, int* __restrict__ cnt)
{
  int blk = blockIdx.x;
  const int* pc; int Z, Y, X; int* base; int i;
  if (blk < 1954)      { pc = i2; Z = Z_1; Y = Y_1; X = X_1; base = cnt + WC1; i = blk * 256 + threadIdx.x; }
  else if (blk < 3908) { pc = i4; Z = Z_2; Y = Y_2; X = X_2; base = cnt + WC2; i = (blk - 1954) * 256 + threadIdx.x; }
  else                 { pc = i8; Z = Z_3; Y = Y_3; X = X_3; base = cnt + WC3; i = (blk - 3908) * 256 + threadIdx.x; }
  if (i >= 500000) return;
  int b = pc[i * 4], z = pc[i * 4 + 1], y = pc[i * 4 + 2], x = pc[i * 4 + 3];
  int lin = ((b * Z + z) * Y + y) * X + x;
  atomicAdd(base + lin * NLAB + lab[i], 1);
}

__global__ __launch_bounds__(256) void k_lbl(
    const int* __restrict__ fc1, const int* __restrict__ fc2, const int* __restrict__ fc3,
    const int* __restrict__ cnt, float* __restrict__ out)
{
  int blk = blockIdx.x;
  const int* fc; int Z, Y, X, M; const int* base; long lbase; int m;
  if (blk < HB1)            { fc = fc1; Z = Z_1; Y = Y_1; X = X_1; M = M_1; base = cnt + WC1; lbase = O_LBL1; m = blk * 256 + threadIdx.x; }
  else if (blk < HB1 + HB2) { fc = fc2; Z = Z_2; Y = Y_2; X = X_2; M = M_2; base = cnt + WC2; lbase = O_LBL2; m = (blk - HB1) * 256 + threadIdx.x; }
  else                      { fc = fc3; Z = Z_3; Y = Y_3; X = X_3; M = M_3; base = cnt + WC3; lbase = O_LBL3; m = (blk - HB1 - HB2) * 256 + threadIdx.x; }
  if (m >= M) return;
  int b = fc[m * 4], z = fc[m * 4 + 1], y = fc[m * 4 + 2], x = fc[m * 4 + 3];
  int lin = ((b * Z + z) * Y + y) * X + x;
  const int* cp = base + lin * NLAB;
  int best = cp[0]; int bi = 0;
#pragma unroll
  for (int n = 1; n < NLAB; n++) { int cc = cp[n]; if (cc > best) { best = cc; bi = n; } }
  out[lbase + m] = (float)bi;
}

// ---------------- head GEMM: h = bf16(x) @ bf16(w1) via MFMA 16x16x32 ----------------
__global__ __launch_bounds__(256) void k_gemm(
    const float* __restrict__ x1, const float* __restrict__ x2, const float* __restrict__ x3,
    const float* __restrict__ w1a, const float* __restrict__ w1b, const float* __restrict__ w1c,
    u16* __restrict__ hbuf, float* __restrict__ part)
{
  int blk = blockIdx.x;
  const float* x; const float* w1; u16* h; float* pp; int Cin, M, bl, NB;
  if (blk < GB1)            { x = x1; w1 = w1a; h = hbuf + WH1; pp = part + WP1; Cin = C_1; M = M_1; bl = blk;             NB = GB1; }
  else if (blk < GB1 + GB2) { x = x2; w1 = w1b; h = hbuf + WH2; pp = part + WP2; Cin = C_2; M = M_2; bl = blk - GB1;       NB = GB2; }
  else                      { x = x3; w1 = w1c; h = hbuf + WH3; pp = part + WP3; Cin = C_3; M = M_3; bl = blk - GB1 - GB2; NB = GB3; }
  int tid = threadIdx.x;
  int lane = tid & 63, wv = tid >> 6;
  int m16 = lane & 15, quad = lane >> 4;

  __shared__ u16 As[128 * 72];
  __shared__ u16 Bs[64 * 72];
  __shared__ float redS[4][64];
  __shared__ float redQ[4][64];

  f32x4 acc[2][4];
#pragma unroll
  for (int mt = 0; mt < 2; mt++)
#pragma unroll
    for (int nt = 0; nt < 4; nt++) acc[mt][nt] = (f32x4){0.f, 0.f, 0.f, 0.f};

  int nchunk = Cin >> 6;
  for (int c = 0; c < nchunk; c++) {
    if (c) __syncthreads();
#pragma unroll
    for (int pass = 0; pass < 8; pass++) {
      int fidx = pass * 256 + tid;
      int row = fidx >> 4, kp = (fidx & 15) * 4;
      int grow = bl * 128 + row;
      float4 v = make_float4(0.f, 0.f, 0.f, 0.f);
      if (grow < M) v = *(const float4*)(x + (size_t)grow * Cin + c * 64 + kp);
      ushort4 o = { f2bf(v.x), f2bf(v.y), f2bf(v.z), f2bf(v.w) };
      *(ushort4*)(As + row * 72 + kp) = o;
    }
    {
      int n = tid & 63, kg = tid >> 6;
#pragma unroll
      for (int p = 0; p < 4; p++) {
        int k0 = kg * 4 + p * 16;
        const float* wp = w1 + (size_t)(c * 64 + k0) * 64 + n;
        ushort4 o = { f2bf(wp[0]), f2bf(wp[64]), f2bf(wp[128]), f2bf(wp[192]) };
        *(ushort4*)(Bs + n * 72 + k0) = o;
      }
    }
    __syncthreads();
#pragma unroll
    for (int ks = 0; ks < 2; ks++) {
      short8 a0 = *(const short8*)(As + (wv * 32 + m16) * 72 + ks * 32 + quad * 8);
      short8 a1 = *(const short8*)(As + (wv * 32 + 16 + m16) * 72 + ks * 32 + quad * 8);
      short8 b[4];
#pragma unroll
      for (int nt = 0; nt < 4; nt++)
        b[nt] = *(const short8*)(Bs + (nt * 16 + m16) * 72 + ks * 32 + quad * 8);
#pragma unroll
      for (int nt = 0; nt < 4; nt++) {
        acc[0][nt] = __builtin_amdgcn_mfma_f32_16x16x32_bf16(a0, b[nt], acc[0][nt], 0, 0, 0);
        acc[1][nt] = __builtin_amdgcn_mfma_f32_16x16x32_bf16(a1, b[nt], acc[1][nt], 0, 0, 0);
      }
    }
  }

  float s[4] = {0.f, 0.f, 0.f, 0.f}, q[4] = {0.f, 0.f, 0.f, 0.f};
#pragma unroll
  for (int mt = 0; mt < 2; mt++) {
#pragma unroll
    for (int nt = 0; nt < 4; nt++) {
#pragma unroll
      for (int r = 0; r < 4; r++) {
        float v = acc[mt][nt][r];
        int grow = bl * 128 + wv * 32 + mt * 16 + quad * 4 + r;
        if (grow < M) h[(size_t)grow * 64 + nt * 16 + m16] = f2bf(v);
        s[nt] += v;
        q[nt] = fmaf(v, v, q[nt]);
      }
    }
  }
#pragma unroll
  for (int nt = 0; nt < 4; nt++) {
    s[nt] += __shfl_xor(s[nt], 16); s[nt] += __shfl_xor(s[nt], 32);
    q[nt] += __shfl_xor(q[nt], 16); q[nt] += __shfl_xor(q[nt], 32);
  }
  if (lane < 16) {
#pragma unroll
    for (int nt = 0; nt < 4; nt++) {
      redS[wv][nt * 16 + lane] = s[nt];
      redQ[wv][nt * 16 + lane] = q[nt];
    }
  }
  __syncthreads();
  if (tid < 64) {
    pp[tid * NB + bl] = redS[0][tid] + redS[1][tid] + redS[2][tid] + redS[3][tid];
  } else if (tid < 128) {
    int n2 = tid - 64;
    pp[(64 + n2) * NB + bl] = redQ[0][n2] + redQ[1][n2] + redQ[2][n2] + redQ[3][n2];
  }
}

// one block per (scale, column): reduce partials, emit fused scale/shift:
// h_norm = h*scale + shift, scale = rsqrt(var+eps)*g, shift = b - mu*scale
__global__ __launch_bounds__(256) void k_stats(const float* __restrict__ part, float* __restrict__ stats,
    const float* __restrict__ g1, const float* __restrict__ b1,
    const float* __restrict__ g4, const float* __restrict__ b4,
    const float* __restrict__ g8, const float* __restrict__ b8)
{
  int blk = blockIdx.x;
  int sc = blk >> 6, col = blk & 63;
  int nb; const float* p; float invM; const float* g; const float* bb;
  if (sc == 0)      { nb = GB1; p = part + WP1; invM = 1.f / M_1; g = g1; bb = b1; }
  else if (sc == 1) { nb = GB2; p = part + WP2; invM = 1.f / M_2; g = g4; bb = b4; }
  else              { nb = GB3; p = part + WP3; invM = 1.f / M_3; g = g8; bb = b8; }
  int t = threadIdx.x;
  const float* ps = p + (size_t)col * nb;
  const float* pq = p + (size_t)(64 + col) * nb;
  float s = 0.f, q = 0.f;
  for (int i = t; i < nb; i += 256) { s += ps[i]; q += pq[i]; }
  __shared__ float r1[256], r2[256];
  r1[t] = s; r2[t] = q;
  __syncthreads();
  for (int off = 128; off > 0; off >>= 1) {
    if (t < off) { r1[t] += r1[t + off]; r2[t] += r2[t + off]; }
    __syncthreads();
  }
  if (t == 0) {
    float mu  = r1[0] * invM;
    float var = r2[0] * invM - mu * mu;
    float scale = rsqrtf(var + 1e-5f) * g[col];
    stats[sc * 128 + col]      = scale;
    stats[sc * 128 + 64 + col] = fmaf(-mu, scale, bb[col]);
  }
}

// ---------------- head epilogue: LDS-staged normalize -> leaky -> @ w2 + b2 ----------------
// block = 256 rows. h tile (32 KB contiguous) staged coalesced into LDS (stride 68 u16).
// Output staged in same LDS (after sync) and written out coalesced.
__global__ __launch_bounds__(256) void k_head(
    const u16* __restrict__ hbuf, const float* __restrict__ stats,
    const float* __restrict__ w21, const float* __restrict__ c21,
    const float* __restrict__ w24, const float* __restrict__ c24,
    const float* __restrict__ w28, const float* __restrict__ c28,
    float* __restrict__ out)
{
  int blk = blockIdx.x;
  const u16* h; const float* st; const float* w2; const float* b2;
  int M; long obase; int bl;
  if (blk < HB1)            { h = hbuf + WH1; st = stats;       w2 = w21; b2 = c21; M = M_1; obase = O_LOG1; bl = blk; }
  else if (blk < HB1 + HB2) { h = hbuf + WH2; st = stats + 128; w2 = w24; b2 = c24; M = M_2; obase = O_LOG2; bl = blk - HB1; }
  else                      { h = hbuf + WH3; st = stats + 256; w2 = w28; b2 = c28; M = M_3; obase = O_LOG3; bl = blk - HB1 - HB2; }
  int tid = threadIdx.x;
  int rowbase = bl * 256;
  int avail = M - rowbase; if (avail > 256) avail = 256;

  __shared__ __align__(16) u16 hs[256 * 68];
  float* os = (float*)hs;   // reused after compute phase (sync-separated)

  // stage-in: tile is contiguous in global -> fully coalesced uint4 loads.
  // 256 rows x 8 uint4/row = 2048 uint4 -> 8 passes of 256 threads.
  const uint4* src = (const uint4*)(h + (size_t)rowbase * 64);
  int n4 = avail * 8;
#pragma unroll
  for (int pass = 0; pass < 8; pass++) {
    int e4 = pass * 256 + tid;
    if (e4 < n4) {
      uint4 v = src[e4];
      int row = e4 >> 3, c = (e4 & 7) * 8;
      uint2 lo = { v.x, v.y }, hi = { v.z, v.w };
      *(uint2*)(hs + row * 68 + c)     = lo;
      *(uint2*)(hs + row * 68 + c + 4) = hi;
    }
  }
  __syncthreads();

  float acc[19];
#pragma unroll
  for (int n = 0; n < 19; n++) acc[n] = 0.f;
  if (tid < avail) {
    const u16* hr = hs + tid * 68;
#pragma unroll
    for (int jg = 0; jg < 16; jg++) {
      uint2 d = *(const uint2*)(hr + jg * 4);
      int j = jg * 4;
      float f0 = __uint_as_float(d.x << 16);
      float f1 = __uint_as_float(d.x & 0xffff0000u);
      float f2 = __uint_as_float(d.y << 16);
      float f3 = __uint_as_float(d.y & 0xffff0000u);
      float a0 = fmaf(f0, st[j],     st[64 + j]);     a0 = a0 >= 0.f ? a0 : 0.1f * a0;
      float a1 = fmaf(f1, st[j + 1], st[64 + j + 1]); a1 = a1 >= 0.f ? a1 : 0.1f * a1;
      float a2 = fmaf(f2, st[j + 2], st[64 + j + 2]); a2 = a2 >= 0.f ? a2 : 0.1f * a2;
      float a3 = fmaf(f3, st[j + 3], st[64 + j + 3]); a3 = a3 >= 0.f ? a3 : 0.1f * a3;
#pragma unroll
      for (int n = 0; n < 19; n++) {
        acc[n] = fmaf(a0, w2[j * 19 + n], acc[n]);
        acc[n] = fmaf(a1, w2[(j + 1) * 19 + n], acc[n]);
        acc[n] = fmaf(a2, w2[(j + 2) * 19 + n], acc[n]);
        acc[n] = fmaf(a3, w2[(j + 3) * 19 + n], acc[n]);
      }
    }
  }
  __syncthreads();   // all LDS h reads done; reuse as output buffer
  if (tid < avail) {
#pragma unroll
    for (int n = 0; n < 19; n++) os[tid * 19 + n] = acc[n] + b2[n];
  }
  __syncthreads();
  int tot = avail * 19;
  float* op = out + obase + (size_t)rowbase * 19;
  for (int i = tid; i < tot; i += 256) op[i] = os[i];
}

// ---------------- launch ----------------
extern "C" void kernel_launch(void* const* d_in, const int* in_sizes, int n_in,
                              void* d_out, int out_size, void* d_ws, size_t ws_size,
                              hipStream_t stream) {
  (void)in_sizes; (void)n_in; (void)out_size; (void)ws_size;
  const float* p1 = (const float*)d_in[0];
  const float* p2 = (const float*)d_in[1];
  const float* p3 = (const float*)d_in[2];
  const int* vc1  = (const int*)d_in[3];
  const int* vc2  = (const int*)d_in[4];
  const int* vc3  = (const int*)d_in[5];
  const int* i2   = (const int*)d_in[6];
  const int* i4   = (const int*)d_in[7];
  const int* i8   = (const int*)d_in[8];
  const int* lab  = (const int*)d_in[9];
  const float* h2w1 = (const float*)d_in[10]; const float* h2g = (const float*)d_in[11];
  const float* h2b  = (const float*)d_in[12]; const float* h2w2 = (const float*)d_in[13];
  const float* h2b2 = (const float*)d_in[14];
  const float* h4w1 = (const float*)d_in[15]; const float* h4g = (const float*)d_in[16];
  const float* h4b  = (const float*)d_in[17]; const float* h4w2 = (const float*)d_in[18];
  const float* h4b2 = (const float*)d_in[19];
  const float* h8w1 = (const float*)d_in[20]; const float* h8g = (const float*)d_in[21];
  const float* h8b  = (const float*)d_in[22]; const float* h8w2 = (const float*)d_in[23];
  const float* h8b2 = (const float*)d_in[24];

  float* out = (float*)d_out;
  int* wsi = (int*)d_ws;
  float* wsf = (float*)d_ws;
  u16* wsh = (u16*)d_ws;

  // ---- BEV: counting-sort + gather (no global atomic-max) ----
  hipMemsetAsync(wsi + WB_CNT, 0, NCELLS * sizeof(int), stream);
  k_cellcount<<<HB1 + HB2 + HB3, 256, 0, stream>>>(vc1, vc2, vc3, wsi + WB_CNT);
  k_scan<<<1, 1024, 0, stream>>>(wsi + WB_CNT, wsi + WB_CUR);
  k_scatter<<<HB1 + HB2 + HB3, 256, 0, stream>>>(vc1, vc2, vc3, wsi + WB_CUR, wsi + WB_PIDX);
  k_bevg1<<<8192, 256, 0, stream>>>(p1, wsi + WB_CNT, wsi + WB_CUR, wsi + WB_PIDX, out);
  k_bevg2<<<4096, 256, 0, stream>>>(p2, wsi + WB_CNT, wsi + WB_CUR, wsi + WB_PIDX, out);
  k_bevg3<<<1024, 256, 0, stream>>>(p3, wsi + WB_CNT, wsi + WB_CUR, wsi + WB_PIDX, out);

  // ---- semantic targets (reuses ws bytes; stream-ordered after BEV) ----
  hipMemsetAsync(d_ws, 0, W_COUNT_BYTES, stream);
  k_count<<<5862, 256, 0, stream>>>(i2, i4, i8, lab, wsi);
  k_lbl<<<HB1 + HB2 + HB3, 256, 0, stream>>>(vc1, vc2, vc3, wsi, out);

  // ---- heads (h reuses the counts bytes; counts fully consumed by k_lbl) ----
  k_gemm<<<GB1 + GB2 + GB3, 256, 0, stream>>>(p1, p2, p3, h2w1, h4w1, h8w1, wsh, wsf + WPART);
  k_stats<<<192, 256, 0, stream>>>(wsf + WPART, wsf + WSTATS, h2g, h2b, h4g, h4b, h8g, h8b);
  k_head<<<HB1 + HB2 + HB3, 256, 0, stream>>>((const u16*)d_ws, wsf + WSTATS,
      h2w2, h2b2, h4w2, h4b2, h8w2, h8b2, out);
}